// Round 4
// baseline (1323.196 us; speedup 1.0000x reference)
//
#include <hip/hip_runtime.h>
#include <math.h>

#define SP 36864            // 192*192 spatial
#define NC 128              // model dim

typedef unsigned short u16;
typedef __attribute__((ext_vector_type(8))) short short8v;   // 8 bf16 (4 VGPRs)
typedef __attribute__((ext_vector_type(4))) float f32x4;

static __device__ __forceinline__ u16 bf16r(float f) {
    unsigned u = __builtin_bit_cast(unsigned, f);
    u += 0x7fffu + ((u >> 16) & 1u);            // round-to-nearest-even
    return (u16)(u >> 16);
}
static __device__ __forceinline__ float b2f(u16 u) {
    unsigned v = ((unsigned)u) << 16;
    return __builtin_bit_cast(float, v);
}

// ---------------- LayerNorm over channel -> XN bf16 [row][128] --------------
// perm==0: row=(b*192+t), X addr = c*SP + t*192 + b
// perm==1: row=(b*192+t), X addr = c*SP + b*192 + t
__global__ __launch_bounds__(256) void ln_rows_bf16_kernel(
    const float* __restrict__ X, const float* __restrict__ g,
    const float* __restrict__ b, u16* __restrict__ XN, int perm)
{
    int gid = blockIdx.x * 256 + threadIdx.x;      // 0..36863
    int i0 = gid % 192, i1 = gid / 192;
    int sp = i1 * 192 + i0;                        // coalesced along i0
    int row = (perm == 0) ? (i0 * 192 + i1) : gid;
    float sum = 0.f, sq = 0.f;
    for (int c = 0; c < NC; ++c) {
        float v = X[(size_t)c * SP + sp];
        sum += v; sq += v * v;
    }
    float mu  = sum * (1.f / NC);
    float var = sq * (1.f / NC) - mu * mu;
    float rs  = rsqrtf(var + 1e-5f);
    u16* xr = XN + (size_t)row * NC;
    for (int c0 = 0; c0 < 16; ++c0) {
        unsigned pk[4];
        #pragma unroll
        for (int e = 0; e < 4; ++e) {
            int c = c0 * 8 + e * 2;
            float v0 = (X[(size_t)c * SP + sp]       - mu) * rs * g[c]     + b[c];
            float v1 = (X[(size_t)(c + 1) * SP + sp] - mu) * rs * g[c + 1] + b[c + 1];
            pk[e] = (unsigned)bf16r(v0) | ((unsigned)bf16r(v1) << 16);
        }
        *(uint4*)&xr[c0 * 8] = make_uint4(pk[0], pk[1], pk[2], pk[3]);
    }
}

// -------- weight repack f32 [K][N] -> bf16 [N][K], batched over blockIdx.y --
__global__ __launch_bounds__(256) void repack_t_kernel(
    const float* __restrict__ in, u16* __restrict__ out, int K, int N)
{
    const float* ib = in + (size_t)blockIdx.y * K * N;
    u16* ob = out + (size_t)blockIdx.y * K * N;
    int o = blockIdx.x * 256 + threadIdx.x;
    if (o >= K * N) return;
    int n = o / K, k = o - n * K;
    ob[o] = bf16r(ib[(size_t)k * N + n]);
}

// ---------------- bf16 MFMA GEMM: A[M][KD] @ BT[N][KD]^T --------------------
// tile 128m x 64n, 4 waves (32m x 64n each), BK=64, swizzled LDS.
// MODE 0: Q epilogue (scale, -> O0[bh][t][32]); MODE 1: KV epilogue.
template<int KD, int MODE>
__global__ __launch_bounds__(256) void gemm_qkv_kernel(
    const u16* __restrict__ A, const u16* __restrict__ BT,
    u16* __restrict__ O0, u16* __restrict__ O1, float scale)
{
    __shared__ __align__(16) u16 As[128 * 64];
    __shared__ __align__(16) u16 Bs[64 * 64];
    const int m0 = blockIdx.y * 128, n0 = blockIdx.x * 64;
    const int tid = threadIdx.x, lane = tid & 63, wave = tid >> 6;
    const int lrow = lane & 15, g = lane >> 4;
    f32x4 acc[2][4];
    #pragma unroll
    for (int i = 0; i < 2; ++i)
        #pragma unroll
        for (int j = 0; j < 4; ++j) acc[i][j] = (f32x4){0.f, 0.f, 0.f, 0.f};

    for (int k0 = 0; k0 < KD; k0 += 64) {
        #pragma unroll
        for (int i = 0; i < 4; ++i) {
            int F = tid + i * 256;
            int row = F >> 3, wn = (F & 7) * 16;
            int sw = wn ^ ((row & 7) << 4);
            *(uint4*)&As[F * 8] = *(const uint4*)&A[(size_t)(m0 + row) * KD + k0 + (sw >> 1)];
        }
        #pragma unroll
        for (int i = 0; i < 2; ++i) {
            int F = tid + i * 256;
            int n = F >> 3, wn = (F & 7) * 16;
            int sw = wn ^ ((n & 7) << 4);
            *(uint4*)&Bs[F * 8] = *(const uint4*)&BT[(size_t)(n0 + n) * KD + k0 + (sw >> 1)];
        }
        __syncthreads();
        #pragma unroll
        for (int ks = 0; ks < 2; ++ks) {
            short8v af[2], bf[4];
            #pragma unroll
            for (int mt = 0; mt < 2; ++mt) {
                int row = wave * 32 + mt * 16 + lrow;
                int off = ((ks * 64 + g * 16) ^ ((row & 7) << 4)) >> 1;
                af[mt] = *(const short8v*)&As[row * 64 + off];
            }
            #pragma unroll
            for (int nt = 0; nt < 4; ++nt) {
                int n = nt * 16 + lrow;
                int off = ((ks * 64 + g * 16) ^ ((n & 7) << 4)) >> 1;
                bf[nt] = *(const short8v*)&Bs[n * 64 + off];
            }
            #pragma unroll
            for (int mt = 0; mt < 2; ++mt)
                #pragma unroll
                for (int nt = 0; nt < 4; ++nt)
                    acc[mt][nt] = __builtin_amdgcn_mfma_f32_16x16x32_bf16(
                        af[mt], bf[nt], acc[mt][nt], 0, 0, 0);
        }
        __syncthreads();
    }
    #pragma unroll
    for (int mt = 0; mt < 2; ++mt) {
        #pragma unroll
        for (int r = 0; r < 4; ++r) {
            int m = m0 + wave * 32 + mt * 16 + 4 * g + r;
            int bq = m / 192, t = m - bq * 192;
            #pragma unroll
            for (int nt = 0; nt < 4; ++nt) {
                int n = n0 + nt * 16 + lrow;
                float v = acc[mt][nt][r];
                if (MODE == 0) {
                    O0[((size_t)(bq * 8 + (n >> 5)) * 192 + t) * 32 + (n & 31)] = bf16r(v * scale);
                } else {
                    u16* dst = (n < 256) ? O0 : O1;
                    int nn = n & 255;
                    dst[((size_t)(bq * 8 + (nn >> 5)) * 192 + t) * 32 + (nn & 31)] = bf16r(v);
                }
            }
        }
    }
}

// ---------------- Wo GEMM: AO[36864][256] @ WoT[128][256]^T + bias -> X -----
// PERM0 uses row-permuted logical m so X writes are coalesced for both perms.
template<int PERM>
__global__ __launch_bounds__(256) void gemm_wo_kernel(
    const u16* __restrict__ A, const u16* __restrict__ BT,
    const float* __restrict__ bias, float* __restrict__ X)
{
    __shared__ __align__(16) char smem[64 * 132 * 4];    // 33792 B
    u16* As = (u16*)smem;                 // [128][64]
    u16* Bs = (u16*)(smem + 16384);       // [64][64]
    float (*et)[132] = (float (*)[132])smem;
    const int m0 = blockIdx.y * 128, n0 = blockIdx.x * 64;
    const int tid = threadIdx.x, lane = tid & 63, wave = tid >> 6;
    const int lrow = lane & 15, g = lane >> 4;
    f32x4 acc[2][4];
    #pragma unroll
    for (int i = 0; i < 2; ++i)
        #pragma unroll
        for (int j = 0; j < 4; ++j) acc[i][j] = (f32x4){0.f, 0.f, 0.f, 0.f};

    for (int k0 = 0; k0 < 256; k0 += 64) {
        #pragma unroll
        for (int i = 0; i < 4; ++i) {
            int F = tid + i * 256;
            int row = F >> 3, wn = (F & 7) * 16;
            int sw = wn ^ ((row & 7) << 4);
            int ml = m0 + row;
            int ra = (PERM == 0) ? ((ml % 192) * 192 + ml / 192) : ml;
            *(uint4*)&As[F * 8] = *(const uint4*)&A[(size_t)ra * 256 + k0 + (sw >> 1)];
        }
        #pragma unroll
        for (int i = 0; i < 2; ++i) {
            int F = tid + i * 256;
            int n = F >> 3, wn = (F & 7) * 16;
            int sw = wn ^ ((n & 7) << 4);
            *(uint4*)&Bs[F * 8] = *(const uint4*)&BT[(size_t)(n0 + n) * 256 + k0 + (sw >> 1)];
        }
        __syncthreads();
        #pragma unroll
        for (int ks = 0; ks < 2; ++ks) {
            short8v af[2], bf[4];
            #pragma unroll
            for (int mt = 0; mt < 2; ++mt) {
                int row = wave * 32 + mt * 16 + lrow;
                int off = ((ks * 64 + g * 16) ^ ((row & 7) << 4)) >> 1;
                af[mt] = *(const short8v*)&As[row * 64 + off];
            }
            #pragma unroll
            for (int nt = 0; nt < 4; ++nt) {
                int n = nt * 16 + lrow;
                int off = ((ks * 64 + g * 16) ^ ((n & 7) << 4)) >> 1;
                bf[nt] = *(const short8v*)&Bs[n * 64 + off];
            }
            #pragma unroll
            for (int mt = 0; mt < 2; ++mt)
                #pragma unroll
                for (int nt = 0; nt < 4; ++nt)
                    acc[mt][nt] = __builtin_amdgcn_mfma_f32_16x16x32_bf16(
                        af[mt], bf[nt], acc[mt][nt], 0, 0, 0);
        }
        __syncthreads();
    }
    __syncthreads();
    #pragma unroll
    for (int mt = 0; mt < 2; ++mt)
        #pragma unroll
        for (int nt = 0; nt < 4; ++nt)
            #pragma unroll
            for (int r = 0; r < 4; ++r)
                et[nt * 16 + lrow][wave * 32 + mt * 16 + 4 * g + r] = acc[mt][nt][r];
    __syncthreads();
    int nl = tid >> 2, mseg = (tid & 3) * 32;
    float bb = bias[n0 + nl];
    #pragma unroll
    for (int q = 0; q < 8; ++q) {
        float4 v;
        v.x = et[nl][mseg + q * 4 + 0] + bb;
        v.y = et[nl][mseg + q * 4 + 1] + bb;
        v.z = et[nl][mseg + q * 4 + 2] + bb;
        v.w = et[nl][mseg + q * 4 + 3] + bb;
        *(float4*)&X[(size_t)(n0 + nl) * SP + m0 + mseg + q * 4] = v;
    }
}

// ------ dynamic projection + landmark + fused lk-LayerNorm (bf16 K/V) -------
__global__ __launch_bounds__(256) void proj_lkln_kernel(
    u16* __restrict__ Kb, const u16* __restrict__ Vb,
    const float* __restrict__ wp, const float* __restrict__ lnl_g,
    const float* __restrict__ lnl_b, const float* __restrict__ lng_g,
    const float* __restrict__ lng_b, float* __restrict__ GK, float* __restrict__ GV)
{
    int bh = blockIdx.x, tid = threadIdx.x;
    size_t base = (size_t)bh * 6144;
    __shared__ float wps[32], sc[192], red[1], gkr[32];
    if (tid < 32) wps[tid] = wp[tid];
    __syncthreads();
    float kr[32]; float ksum = 0.f, ksq = 0.f;
    if (tid < 192) {
        float s = 0.f;
        #pragma unroll
        for (int p2 = 0; p2 < 4; ++p2) {
            short8v kv = *(const short8v*)&Kb[base + tid * 32 + p2 * 8];
            #pragma unroll
            for (int j = 0; j < 8; ++j) {
                float v = b2f((u16)kv[j]);
                kr[p2 * 8 + j] = v; s += v * wps[p2 * 8 + j];
                ksum += v; ksq += v * v;
            }
        }
        sc[tid] = s;
    }
    __syncthreads();
    if (tid < 64) {
        float m = fmaxf(fmaxf(sc[tid], sc[tid + 64]), sc[tid + 128]);
        for (int o = 32; o; o >>= 1) m = fmaxf(m, __shfl_xor(m, o));
        if (!tid) red[0] = m;
    }
    __syncthreads();
    float mx = red[0];
    if (tid < 192) sc[tid] = __expf(sc[tid] - mx);
    __syncthreads();
    if (tid < 64) {
        float s2 = sc[tid] + sc[tid + 64] + sc[tid + 128];
        for (int o = 32; o; o >>= 1) s2 += __shfl_xor(s2, o);
        if (!tid) red[0] = s2;
    }
    __syncthreads();
    float invs = 1.f / red[0];
    if (tid < 192) sc[tid] *= invs;
    __syncthreads();
    if (tid < 32) {
        float ka = 0.f, va = 0.f;
        for (int t = 0; t < 192; ++t) {
            float p = sc[t];
            ka += p * b2f(Kb[base + t * 32 + tid]);
            va += p * b2f(Vb[base + t * 32 + tid]);
        }
        gkr[tid] = ka;
        GV[(size_t)bh * 32 + tid] = va;
    }
    __syncthreads();
    if (tid < 32) {
        float mu = 0.f;
        for (int d = 0; d < 32; ++d) mu += gkr[d];
        mu *= (1.f / 32);
        float var = 0.f;
        for (int d = 0; d < 32; ++d) { float df = gkr[d] - mu; var += df * df; }
        var *= (1.f / 32);
        float rs = rsqrtf(var + 1e-5f);
        GK[(size_t)bh * 32 + tid] = (gkr[tid] - mu) * rs * lng_g[tid] + lng_b[tid];
    }
    __syncthreads();                 // raw K fully consumed; safe to overwrite
    if (tid < 192) {
        float mu = ksum * (1.f / 32);
        float var = ksq * (1.f / 32) - mu * mu;
        float rs = rsqrtf(var + 1e-5f);
        #pragma unroll
        for (int p2 = 0; p2 < 4; ++p2) {
            unsigned pk[4];
            #pragma unroll
            for (int e = 0; e < 4; ++e) {
                int c = p2 * 8 + e * 2;
                float v0 = (kr[c]     - mu) * rs * lnl_g[c]     + lnl_b[c];
                float v1 = (kr[c + 1] - mu) * rs * lnl_g[c + 1] + lnl_b[c + 1];
                pk[e] = (unsigned)bf16r(v0) | ((unsigned)bf16r(v1) << 16);
            }
            *(uint4*)&Kb[base + tid * 32 + p2 * 8] = make_uint4(pk[0], pk[1], pk[2], pk[3]);
        }
    }
}

// ---------------- MFMA windowed attention + landmark ------------------------
// block per (b,h); 4 waves; swapped QK^T so softmax is lane-local.
__global__ __launch_bounds__(256) void attn_mfma_kernel(
    const u16* __restrict__ Q, const u16* __restrict__ K, const u16* __restrict__ V,
    const float* __restrict__ GK, const float* __restrict__ GV, u16* __restrict__ AO)
{
    __shared__ __align__(16) u16 Ks[192][40];
    __shared__ __align__(16) u16 VTs[32][200];
    __shared__ __align__(16) u16 Ps[4][16][200];
    __shared__ float gks[32], gvs[32], sgs[192];
    const int bh = blockIdx.x, tid = threadIdx.x;
    const int lane = tid & 63, wave = tid >> 6, lrow = lane & 15, g = lane >> 4;
    const size_t base = (size_t)bh * 6144;

    if (tid < 32) { gks[tid] = GK[(size_t)bh * 32 + tid]; gvs[tid] = GV[(size_t)bh * 32 + tid]; }
    __syncthreads();
    #pragma unroll
    for (int i = 0; i < 3; ++i) {
        int f = tid + i * 256;             // 768 16B chunks
        int key = f >> 2, part = f & 3;
        *(uint4*)&Ks[key][part * 8] = *(const uint4*)&K[base + key * 32 + part * 8];
        uint4 vv = *(const uint4*)&V[base + key * 32 + part * 8];
        u16 tmp[8]; *(uint4*)tmp = vv;
        #pragma unroll
        for (int e = 0; e < 8; ++e) VTs[part * 8 + e][key] = tmp[e];
    }
    if (tid < 192) {
        float s = 0.f;
        #pragma unroll
        for (int p2 = 0; p2 < 4; ++p2) {
            short8v qv = *(const short8v*)&Q[base + tid * 32 + p2 * 8];
            #pragma unroll
            for (int j = 0; j < 8; ++j) s += b2f((u16)qv[j]) * gks[p2 * 8 + j];
        }
        sgs[tid] = s;
    }
    __syncthreads();

    for (int qi = 0; qi < 3; ++qi) {
        int qt = wave * 3 + qi;
        int q = qt * 16 + lrow;
        int ww = qt >> 2;
        int tlo = (ww == 0) ? 0 : (ww - 1) * 4;
        int thi = (ww == 2) ? 12 : (ww + 2) * 4;
        short8v qf = *(const short8v*)&Q[base + q * 32 + g * 8];
        f32x4 s[12];
        #pragma unroll
        for (int t = 0; t < 12; ++t) {
            if (t >= tlo && t < thi) {
                short8v kf = *(const short8v*)&Ks[t * 16 + lrow][g * 8];
                f32x4 z = (f32x4){0.f, 0.f, 0.f, 0.f};
                s[t] = __builtin_amdgcn_mfma_f32_16x16x32_bf16(kf, qf, z, 0, 0, 0);
            }
        }
        float sg = sgs[q];
        float m = sg;
        #pragma unroll
        for (int t = 0; t < 12; ++t) if (t >= tlo && t < thi)
            m = fmaxf(m, fmaxf(fmaxf(s[t][0], s[t][1]), fmaxf(s[t][2], s[t][3])));
        m = fmaxf(m, __shfl_xor(m, 16));
        m = fmaxf(m, __shfl_xor(m, 32));
        float l = 0.f;
        #pragma unroll
        for (int t = 0; t < 12; ++t) if (t >= tlo && t < thi) {
            #pragma unroll
            for (int r = 0; r < 4; ++r) { float p = __expf(s[t][r] - m); s[t][r] = p; l += p; }
        }
        l += __shfl_xor(l, 16);
        l += __shfl_xor(l, 32);
        float eg = __expf(sg - m);
        float inv = 1.f / (l + eg);
        float pgv = eg * inv;
        #pragma unroll
        for (int t = 0; t < 12; ++t) if (t >= tlo && t < thi) {
            unsigned u0 = (unsigned)bf16r(s[t][0] * inv) | ((unsigned)bf16r(s[t][1] * inv) << 16);
            unsigned u1 = (unsigned)bf16r(s[t][2] * inv) | ((unsigned)bf16r(s[t][3] * inv) << 16);
            *(uint2*)&Ps[wave][lrow][t * 16 + g * 4] = make_uint2(u0, u1);
        }
        f32x4 o[2] = {(f32x4){0.f,0.f,0.f,0.f}, (f32x4){0.f,0.f,0.f,0.f}};
        int slo = tlo >> 1, shi = thi >> 1;
        #pragma unroll
        for (int ss = 0; ss < 6; ++ss) if (ss >= slo && ss < shi) {
            short8v pa = *(const short8v*)&Ps[wave][lrow][ss * 32 + g * 8];
            #pragma unroll
            for (int dt = 0; dt < 2; ++dt) {
                short8v vb = *(const short8v*)&VTs[dt * 16 + lrow][ss * 32 + g * 8];
                o[dt] = __builtin_amdgcn_mfma_f32_16x16x32_bf16(pa, vb, o[dt], 0, 0, 0);
            }
        }
        int b = bh >> 3, h = bh & 7;
        #pragma unroll
        for (int r = 0; r < 4; ++r) {
            int qg = qt * 16 + 4 * g + r;
            float pg = __shfl(pgv, 4 * g + r);
            size_t rowbase = ((size_t)b * 192 + qg) * 256 + h * 32;
            #pragma unroll
            for (int dt = 0; dt < 2; ++dt) {
                int d = dt * 16 + lrow;
                AO[rowbase + d] = bf16r(o[dt][r] + pg * gvs[d]);
            }
        }
    }
}

// -------- ChanLayerNorm -> bf16 [sp][128] (conv1 input) ---------------------
__global__ __launch_bounds__(256) void chanln_bf16_kernel(
    const float* __restrict__ X, const float* __restrict__ g,
    const float* __restrict__ b, u16* __restrict__ out)
{
    int tid = threadIdx.x;
    int p = tid >> 2, qc = tid & 3;
    int pos = blockIdx.x * 64 + p;
    float xv[32];
    float sum = 0.f, sumsq = 0.f;
    #pragma unroll
    for (int c = 0; c < 32; ++c) {
        float v = X[(size_t)(qc * 32 + c) * SP + pos];
        xv[c] = v; sum += v; sumsq += v * v;
    }
    sum += __shfl_xor(sum, 1);  sum += __shfl_xor(sum, 2);
    sumsq += __shfl_xor(sumsq, 1); sumsq += __shfl_xor(sumsq, 2);
    float mu  = sum * (1.f / 128);
    float var = sumsq * (1.f / 128) - mu * mu;
    float inv = 1.f / (sqrtf(fmaxf(var, 0.f)) + 1e-5f);
    unsigned pk[16];
    #pragma unroll
    for (int c = 0; c < 16; ++c) {
        int c0 = qc * 32 + 2 * c;
        float v0 = (xv[2 * c]     - mu) * inv * g[c0]     + b[c0];
        float v1 = (xv[2 * c + 1] - mu) * inv * g[c0 + 1] + b[c0 + 1];
        pk[c] = (unsigned)bf16r(v0) | ((unsigned)bf16r(v1) << 16);
    }
    uint4* dst = (uint4*)(out + (size_t)pos * 128 + qc * 32);
    #pragma unroll
    for (int q = 0; q < 4; ++q)
        dst[q] = make_uint4(pk[4*q], pk[4*q+1], pk[4*q+2], pk[4*q+3]);
}

// -------- conv weight repack (co,ci,3,3) f32 -> bf16 [tap][CO][CI], batched -
__global__ __launch_bounds__(256) void wtrans_kernel(
    const float* __restrict__ w, u16* __restrict__ wT, int CO, int CI)
{
    const float* wb = w + (size_t)blockIdx.y * CO * CI * 9;
    u16* wTb = wT + (size_t)blockIdx.y * CO * CI * 9;
    int gidx = blockIdx.x * 256 + threadIdx.x;   // co*CI + ci
    if (gidx >= CO * CI) return;
    const float* src = wb + (size_t)gidx * 9;
    #pragma unroll
    for (int k = 0; k < 9; ++k)
        wTb[(size_t)k * CO * CI + gidx] = bf16r(src[k]);
}

// ---------------- bf16 MFMA implicit-GEMM 3x3 conv (v2) ---------------------
// in: [SP][CI] bf16. wT: [9][CO][CI] bf16 (loaded direct global->reg, L2-hot).
// block: 4 y-rows x 64 x x 64 co; wave = one y-row (64 sp x 64 co, acc 4x4).
// LDS: input halo only, [6][66][40] bf16 = 31680 B.
// MODE 0: out bf16 [SP][CO], +bias, leaky.  MODE 1: out f32 [CO][SP], +bias.
template<int CI, int CO, int MODE>
__global__ __launch_bounds__(256) void conv_mfma_kernel(
    const u16* __restrict__ in, const u16* __restrict__ wT,
    const float* __restrict__ bias, void* __restrict__ outp)
{
    __shared__ __align__(16) u16 in_s[6][66][40];   // 31680 B
    const int x0  = blockIdx.x * 64;
    const int y0  = blockIdx.y * 4;
    const int co0 = blockIdx.z * 64;
    const int tid = threadIdx.x;
    const int lane = tid & 63, wave = tid >> 6;
    const int lrow = lane & 15, g = lane >> 4;

    f32x4 acc[4][4];
    #pragma unroll
    for (int i = 0; i < 4; ++i)
        #pragma unroll
        for (int j = 0; j < 4; ++j) acc[i][j] = (f32x4){0.f, 0.f, 0.f, 0.f};

    for (int cc = 0; cc < CI / 32; ++cc) {
        // stage input halo: 6 rows x 66 x x 32 ci  (1584 16B chunks)
        for (int idx = tid; idx < 1584; idx += 256) {
            int r = idx >> 2, p = idx & 3;
            int yy = r / 66, xx = r % 66;
            int gy = y0 + yy - 1, gx = x0 + xx - 1;
            uint4 val = make_uint4(0u, 0u, 0u, 0u);
            if ((unsigned)gy < 192u && (unsigned)gx < 192u)
                val = *(const uint4*)&in[((size_t)gy * 192 + gx) * CI + cc * 32 + p * 8];
            *(uint4*)&in_s[yy][xx][p * 8] = val;
        }
        __syncthreads();
        #pragma unroll
        for (int ky = 0; ky < 3; ++ky) {
            #pragma unroll
            for (int kx = 0; kx < 3; ++kx) {
                short8v bfr[4];
                #pragma unroll
                for (int fn = 0; fn < 4; ++fn)
                    bfr[fn] = *(const short8v*)&wT[
                        ((size_t)(ky * 3 + kx) * CO + co0 + fn * 16 + lrow) * CI + cc * 32 + g * 8];
                #pragma unroll
                for (int fm = 0; fm < 4; ++fm) {
                    short8v a = *(const short8v*)&in_s[wave + ky][fm * 16 + lrow + kx][g * 8];
                    #pragma unroll
                    for (int fn = 0; fn < 4; ++fn)
                        acc[fm][fn] = __builtin_amdgcn_mfma_f32_16x16x32_bf16(
                            a, bfr[fn], acc[fm][fn], 0, 0, 0);
                }
            }
        }
        __syncthreads();
    }

    if (MODE == 0) {
        u16* out = (u16*)outp;
        const int y = y0 + wave;
        #pragma unroll
        for (int fn = 0; fn < 4; ++fn) {
            int co = co0 + fn * 16 + lrow;
            float bb = bias[co];
            #pragma unroll
            for (int fm = 0; fm < 4; ++fm) {
                #pragma unroll
                for (int r = 0; r < 4; ++r) {
                    int i = fm * 16 + g * 4 + r;
                    float v = acc[fm][fn][r] + bb;
                    v = (v >= 0.f) ? v : 0.01f * v;
                    out[((size_t)y * 192 + x0 + i) * CO + co] = bf16r(v);
                }
            }
        }
    } else {
        float* out = (float*)outp;
        // per-wave transpose through (dead) input LDS: et[64 x][17] f32
        float (*et)[17] = (float (*)[17])((char*)in_s + wave * 4352);
        #pragma unroll
        for (int fn = 0; fn < 4; ++fn) {
            #pragma unroll
            for (int fm = 0; fm < 4; ++fm)
                #pragma unroll
                for (int r = 0; r < 4; ++r)
                    et[fm * 16 + g * 4 + r][lrow] = acc[fm][fn][r];
            __syncthreads();
            #pragma unroll
            for (int c2 = 0; c2 < 16; ++c2) {
                int co = co0 + fn * 16 + c2;
                float v = et[lane][c2] + bias[co];
                out[(size_t)co * SP + (y0 + wave) * 192 + x0 + lane] = v;
            }
            __syncthreads();
        }
    }
}

// ---------------------------------------------------------------------------
extern "C" void kernel_launch(void* const* d_in, const int* in_sizes, int n_in,
                              void* d_out, int out_size, void* d_ws, size_t ws_size,
                              hipStream_t stream)
{
    const float* x_in    = (const float*)d_in[0];
    const float* ln_g    = (const float*)d_in[1];
    const float* ln_b    = (const float*)d_in[2];
    const float* Wq      = (const float*)d_in[3];
    const float* Wkv     = (const float*)d_in[4];
    const float* Wproj   = (const float*)d_in[5];
    const float* lnl_g   = (const float*)d_in[6];
    const float* lnl_b   = (const float*)d_in[7];
    const float* lng_g   = (const float*)d_in[8];
    const float* lng_b   = (const float*)d_in[9];
    const float* Wo      = (const float*)d_in[10];
    const float* bo      = (const float*)d_in[11];
    const float* cln_g   = (const float*)d_in[12];
    const float* cln_b   = (const float*)d_in[13];
    const float* conv1_w = (const float*)d_in[14];
    const float* conv1_b = (const float*)d_in[15];
    const float* conv2_w = (const float*)d_in[16];
    const float* conv2_b = (const float*)d_in[17];

    float* X = (float*)d_out;
    char* ws = (char*)d_ws;
    u16*   XN   = (u16*)(ws);                        //  9,437,184 B
    u16*   AO   = (u16*)(ws + 9437184);              // 18,874,368
    u16*   Qb   = (u16*)(ws + 28311552);             // 18,874,368
    u16*   Kb   = (u16*)(ws + 47185920);             // 18,874,368
    u16*   Vb   = (u16*)(ws + 66060288);             // 18,874,368
    float* GK   = (float*)(ws + 84934656);           //    196,608
    float* GV   = (float*)(ws + 85131264);           //    196,608
    u16*   wqT  = (u16*)(ws + 85327872);             //    262,144
    u16*   wkvT = (u16*)(ws + 85590016);             //    524,288
    u16*   woT  = (u16*)(ws + 86114304);             //    262,144
    u16*   wT1  = (u16*)(ws + 86376448);             //  2,359,296
    u16*   wT2  = (u16*)(ws + 88735744);             //  2,359,296
    u16*   XNc16 = XN;                               // conv aliases
    u16*   HID16 = Qb;                               // spans Qb+Kb (37.75MB)

    hipMemcpyAsync(X, x_in, (size_t)SP * NC * 4, hipMemcpyDeviceToDevice, stream);

    repack_t_kernel<<<dim3(128, 4), 256, 0, stream>>>(Wq, wqT, 128, 256);
    repack_t_kernel<<<dim3(256, 4), 256, 0, stream>>>(Wkv, wkvT, 128, 512);
    repack_t_kernel<<<dim3(128, 4), 256, 0, stream>>>(Wo, woT, 256, 128);
    wtrans_kernel<<<dim3(256, 2), 256, 0, stream>>>(conv1_w, wT1, 512, 128);
    wtrans_kernel<<<dim3(256, 2), 256, 0, stream>>>(conv2_w, wT2, 128, 512);

    const float qscale = 0.17677669529663687f;  // 32^-0.5

    for (int l = 0; l < 2; ++l) {
        for (int a = 0; a < 2; ++a) {
            int la = l * 2 + a;
            ln_rows_bf16_kernel<<<144, 256, 0, stream>>>(
                X, ln_g + la * 128, ln_b + la * 128, XN, a);
            gemm_qkv_kernel<128, 0><<<dim3(4, 288), 256, 0, stream>>>(
                XN, wqT + (size_t)la * 32768, Qb, nullptr, qscale);
            gemm_qkv_kernel<128, 1><<<dim3(8, 288), 256, 0, stream>>>(
                XN, wkvT + (size_t)la * 65536, Kb, Vb, 1.f);
            proj_lkln_kernel<<<1536, 256, 0, stream>>>(
                Kb, Vb, Wproj + la * 32, lnl_g + la * 32, lnl_b + la * 32,
                lng_g + la * 32, lng_b + la * 32, GK, GV);
            attn_mfma_kernel<<<1536, 256, 0, stream>>>(Qb, Kb, Vb, GK, GV, AO);
            if (a == 0)
                gemm_wo_kernel<0><<<dim3(2, 288), 256, 0, stream>>>(
                    AO, woT + (size_t)la * 32768, bo + la * 128, X);
            else
                gemm_wo_kernel<1><<<dim3(2, 288), 256, 0, stream>>>(
                    AO, woT + (size_t)la * 32768, bo + la * 128, X);
        }
        chanln_bf16_kernel<<<576, 256, 0, stream>>>(X, cln_g + l * 128, cln_b + l * 128, XNc16);
        conv_mfma_kernel<128, 512, 0><<<dim3(3, 48, 8), 256, 0, stream>>>(
            XNc16, wT1 + (size_t)l * 589824, conv1_b + l * 512, (void*)HID16);
        conv_mfma_kernel<512, 128, 1><<<dim3(3, 48, 2), 256, 0, stream>>>(
            HID16, wT2 + (size_t)l * 589824, conv2_b + l * 128, (void*)X);
    }
}

// Round 5
// 1164.246 us; speedup vs baseline: 1.1365x; 1.1365x over previous
//
#include <hip/hip_runtime.h>
#include <math.h>

#define SP 36864            // 192*192 spatial
#define NC 128              // model dim
#define PW 194              // padded width (192 + 1 halo each side)
#define PSP (PW*PW)         // 37636 padded spatial

typedef unsigned short u16;
typedef __attribute__((ext_vector_type(8))) short short8v;   // 8 bf16 (4 VGPRs)
typedef __attribute__((ext_vector_type(4))) float f32x4;

static __device__ __forceinline__ u16 bf16r(float f) {
    unsigned u = __builtin_bit_cast(unsigned, f);
    u += 0x7fffu + ((u >> 16) & 1u);            // round-to-nearest-even
    return (u16)(u >> 16);
}
static __device__ __forceinline__ float b2f(u16 u) {
    unsigned v = ((unsigned)u) << 16;
    return __builtin_bit_cast(float, v);
}

#define GLOAD_LDS16(gp, lp)                                                     \
    __builtin_amdgcn_global_load_lds(                                           \
        (const __attribute__((address_space(1))) unsigned*)(gp),                \
        (__attribute__((address_space(3))) unsigned*)(lp), 16, 0, 0)

// ---------------- LayerNorm over channel -> XN bf16 [row][128] --------------
// perm==0: row=(b*192+t), X addr = c*SP + t*192 + b
// perm==1: row=(b*192+t), X addr = c*SP + b*192 + t
__global__ __launch_bounds__(256) void ln_rows_bf16_kernel(
    const float* __restrict__ X, const float* __restrict__ g,
    const float* __restrict__ b, u16* __restrict__ XN, int perm)
{
    int gid = blockIdx.x * 256 + threadIdx.x;      // 0..36863
    int i0 = gid % 192, i1 = gid / 192;
    int sp = i1 * 192 + i0;                        // coalesced along i0
    int row = (perm == 0) ? (i0 * 192 + i1) : gid;
    float sum = 0.f, sq = 0.f;
    for (int c = 0; c < NC; ++c) {
        float v = X[(size_t)c * SP + sp];
        sum += v; sq += v * v;
    }
    float mu  = sum * (1.f / NC);
    float var = sq * (1.f / NC) - mu * mu;
    float rs  = rsqrtf(var + 1e-5f);
    u16* xr = XN + (size_t)row * NC;
    for (int c0 = 0; c0 < 16; ++c0) {
        unsigned pk[4];
        #pragma unroll
        for (int e = 0; e < 4; ++e) {
            int c = c0 * 8 + e * 2;
            float v0 = (X[(size_t)c * SP + sp]       - mu) * rs * g[c]     + b[c];
            float v1 = (X[(size_t)(c + 1) * SP + sp] - mu) * rs * g[c + 1] + b[c + 1];
            pk[e] = (unsigned)bf16r(v0) | ((unsigned)bf16r(v1) << 16);
        }
        *(uint4*)&xr[c0 * 8] = make_uint4(pk[0], pk[1], pk[2], pk[3]);
    }
}

// -------- weight repack f32 [K][N] -> bf16 [N][K], batched over blockIdx.y --
__global__ __launch_bounds__(256) void repack_t_kernel(
    const float* __restrict__ in, u16* __restrict__ out, int K, int N)
{
    const float* ib = in + (size_t)blockIdx.y * K * N;
    u16* ob = out + (size_t)blockIdx.y * K * N;
    int o = blockIdx.x * 256 + threadIdx.x;
    if (o >= K * N) return;
    int n = o / K, k = o - n * K;
    ob[o] = bf16r(ib[(size_t)k * N + n]);
}

// ---------------- bf16 MFMA GEMM: A[M][KD] @ BT[N][KD]^T --------------------
// tile 128m x 64n, 4 waves (32m x 64n each), BK=64, swizzled LDS.
// MODE 0: Q epilogue (scale, -> O0[bh][t][32]); MODE 1: KV epilogue.
template<int KD, int MODE>
__global__ __launch_bounds__(256) void gemm_qkv_kernel(
    const u16* __restrict__ A, const u16* __restrict__ BT,
    u16* __restrict__ O0, u16* __restrict__ O1, float scale)
{
    __shared__ __align__(16) u16 As[128 * 64];
    __shared__ __align__(16) u16 Bs[64 * 64];
    const int m0 = blockIdx.y * 128, n0 = blockIdx.x * 64;
    const int tid = threadIdx.x, lane = tid & 63, wave = tid >> 6;
    const int lrow = lane & 15, g = lane >> 4;
    f32x4 acc[2][4];
    #pragma unroll
    for (int i = 0; i < 2; ++i)
        #pragma unroll
        for (int j = 0; j < 4; ++j) acc[i][j] = (f32x4){0.f, 0.f, 0.f, 0.f};

    for (int k0 = 0; k0 < KD; k0 += 64) {
        #pragma unroll
        for (int i = 0; i < 4; ++i) {
            int F = tid + i * 256;
            int row = F >> 3, wn = (F & 7) * 16;
            int sw = wn ^ ((row & 7) << 4);
            *(uint4*)&As[F * 8] = *(const uint4*)&A[(size_t)(m0 + row) * KD + k0 + (sw >> 1)];
        }
        #pragma unroll
        for (int i = 0; i < 2; ++i) {
            int F = tid + i * 256;
            int n = F >> 3, wn = (F & 7) * 16;
            int sw = wn ^ ((n & 7) << 4);
            *(uint4*)&Bs[F * 8] = *(const uint4*)&BT[(size_t)(n0 + n) * KD + k0 + (sw >> 1)];
        }
        __syncthreads();
        #pragma unroll
        for (int ks = 0; ks < 2; ++ks) {
            short8v af[2], bf[4];
            #pragma unroll
            for (int mt = 0; mt < 2; ++mt) {
                int row = wave * 32 + mt * 16 + lrow;
                int off = ((ks * 64 + g * 16) ^ ((row & 7) << 4)) >> 1;
                af[mt] = *(const short8v*)&As[row * 64 + off];
            }
            #pragma unroll
            for (int nt = 0; nt < 4; ++nt) {
                int n = nt * 16 + lrow;
                int off = ((ks * 64 + g * 16) ^ ((n & 7) << 4)) >> 1;
                bf[nt] = *(const short8v*)&Bs[n * 64 + off];
            }
            #pragma unroll
            for (int mt = 0; mt < 2; ++mt)
                #pragma unroll
                for (int nt = 0; nt < 4; ++nt)
                    acc[mt][nt] = __builtin_amdgcn_mfma_f32_16x16x32_bf16(
                        af[mt], bf[nt], acc[mt][nt], 0, 0, 0);
        }
        __syncthreads();
    }
    #pragma unroll
    for (int mt = 0; mt < 2; ++mt) {
        #pragma unroll
        for (int r = 0; r < 4; ++r) {
            int m = m0 + wave * 32 + mt * 16 + 4 * g + r;
            int bq = m / 192, t = m - bq * 192;
            #pragma unroll
            for (int nt = 0; nt < 4; ++nt) {
                int n = n0 + nt * 16 + lrow;
                float v = acc[mt][nt][r];
                if (MODE == 0) {
                    O0[((size_t)(bq * 8 + (n >> 5)) * 192 + t) * 32 + (n & 31)] = bf16r(v * scale);
                } else {
                    u16* dst = (n < 256) ? O0 : O1;
                    int nn = n & 255;
                    dst[((size_t)(bq * 8 + (nn >> 5)) * 192 + t) * 32 + (nn & 31)] = bf16r(v);
                }
            }
        }
    }
}

// ---------------- Wo GEMM: AO[36864][256] @ WoT[128][256]^T + bias -> X -----
// PERM0 uses row-permuted logical m so X writes are coalesced for both perms.
template<int PERM>
__global__ __launch_bounds__(256) void gemm_wo_kernel(
    const u16* __restrict__ A, const u16* __restrict__ BT,
    const float* __restrict__ bias, float* __restrict__ X)
{
    __shared__ __align__(16) char smem[64 * 132 * 4];    // 33792 B
    u16* As = (u16*)smem;                 // [128][64]
    u16* Bs = (u16*)(smem + 16384);       // [64][64]
    float (*et)[132] = (float (*)[132])smem;
    const int m0 = blockIdx.y * 128, n0 = blockIdx.x * 64;
    const int tid = threadIdx.x, lane = tid & 63, wave = tid >> 6;
    const int lrow = lane & 15, g = lane >> 4;
    f32x4 acc[2][4];
    #pragma unroll
    for (int i = 0; i < 2; ++i)
        #pragma unroll
        for (int j = 0; j < 4; ++j) acc[i][j] = (f32x4){0.f, 0.f, 0.f, 0.f};

    for (int k0 = 0; k0 < 256; k0 += 64) {
        #pragma unroll
        for (int i = 0; i < 4; ++i) {
            int F = tid + i * 256;
            int row = F >> 3, wn = (F & 7) * 16;
            int sw = wn ^ ((row & 7) << 4);
            int ml = m0 + row;
            int ra = (PERM == 0) ? ((ml % 192) * 192 + ml / 192) : ml;
            *(uint4*)&As[F * 8] = *(const uint4*)&A[(size_t)ra * 256 + k0 + (sw >> 1)];
        }
        #pragma unroll
        for (int i = 0; i < 2; ++i) {
            int F = tid + i * 256;
            int n = F >> 3, wn = (F & 7) * 16;
            int sw = wn ^ ((n & 7) << 4);
            *(uint4*)&Bs[F * 8] = *(const uint4*)&BT[(size_t)(n0 + n) * 256 + k0 + (sw >> 1)];
        }
        __syncthreads();
        #pragma unroll
        for (int ks = 0; ks < 2; ++ks) {
            short8v af[2], bf[4];
            #pragma unroll
            for (int mt = 0; mt < 2; ++mt) {
                int row = wave * 32 + mt * 16 + lrow;
                int off = ((ks * 64 + g * 16) ^ ((row & 7) << 4)) >> 1;
                af[mt] = *(const short8v*)&As[row * 64 + off];
            }
            #pragma unroll
            for (int nt = 0; nt < 4; ++nt) {
                int n = nt * 16 + lrow;
                int off = ((ks * 64 + g * 16) ^ ((n & 7) << 4)) >> 1;
                bf[nt] = *(const short8v*)&Bs[n * 64 + off];
            }
            #pragma unroll
            for (int mt = 0; mt < 2; ++mt)
                #pragma unroll
                for (int nt = 0; nt < 4; ++nt)
                    acc[mt][nt] = __builtin_amdgcn_mfma_f32_16x16x32_bf16(
                        af[mt], bf[nt], acc[mt][nt], 0, 0, 0);
        }
        __syncthreads();
    }
    __syncthreads();
    #pragma unroll
    for (int mt = 0; mt < 2; ++mt)
        #pragma unroll
        for (int nt = 0; nt < 4; ++nt)
            #pragma unroll
            for (int r = 0; r < 4; ++r)
                et[nt * 16 + lrow][wave * 32 + mt * 16 + 4 * g + r] = acc[mt][nt][r];
    __syncthreads();
    int nl = tid >> 2, mseg = (tid & 3) * 32;
    float bb = bias[n0 + nl];
    #pragma unroll
    for (int q = 0; q < 8; ++q) {
        float4 v;
        v.x = et[nl][mseg + q * 4 + 0] + bb;
        v.y = et[nl][mseg + q * 4 + 1] + bb;
        v.z = et[nl][mseg + q * 4 + 2] + bb;
        v.w = et[nl][mseg + q * 4 + 3] + bb;
        *(float4*)&X[(size_t)(n0 + nl) * SP + m0 + mseg + q * 4] = v;
    }
}

// ------ dynamic projection + landmark + fused lk-LayerNorm (bf16 K/V) -------
__global__ __launch_bounds__(256) void proj_lkln_kernel(
    u16* __restrict__ Kb, const u16* __restrict__ Vb,
    const float* __restrict__ wp, const float* __restrict__ lnl_g,
    const float* __restrict__ lnl_b, const float* __restrict__ lng_g,
    const float* __restrict__ lng_b, float* __restrict__ GK, float* __restrict__ GV)
{
    int bh = blockIdx.x, tid = threadIdx.x;
    size_t base = (size_t)bh * 6144;
    __shared__ float wps[32], sc[192], red[1], gkr[32];
    if (tid < 32) wps[tid] = wp[tid];
    __syncthreads();
    float kr[32]; float ksum = 0.f, ksq = 0.f;
    if (tid < 192) {
        float s = 0.f;
        #pragma unroll
        for (int p2 = 0; p2 < 4; ++p2) {
            short8v kv = *(const short8v*)&Kb[base + tid * 32 + p2 * 8];
            #pragma unroll
            for (int j = 0; j < 8; ++j) {
                float v = b2f((u16)kv[j]);
                kr[p2 * 8 + j] = v; s += v * wps[p2 * 8 + j];
                ksum += v; ksq += v * v;
            }
        }
        sc[tid] = s;
    }
    __syncthreads();
    if (tid < 64) {
        float m = fmaxf(fmaxf(sc[tid], sc[tid + 64]), sc[tid + 128]);
        for (int o = 32; o; o >>= 1) m = fmaxf(m, __shfl_xor(m, o));
        if (!tid) red[0] = m;
    }
    __syncthreads();
    float mx = red[0];
    if (tid < 192) sc[tid] = __expf(sc[tid] - mx);
    __syncthreads();
    if (tid < 64) {
        float s2 = sc[tid] + sc[tid + 64] + sc[tid + 128];
        for (int o = 32; o; o >>= 1) s2 += __shfl_xor(s2, o);
        if (!tid) red[0] = s2;
    }
    __syncthreads();
    float invs = 1.f / red[0];
    if (tid < 192) sc[tid] *= invs;
    __syncthreads();
    if (tid < 32) {
        float ka = 0.f, va = 0.f;
        for (int t = 0; t < 192; ++t) {
            float p = sc[t];
            ka += p * b2f(Kb[base + t * 32 + tid]);
            va += p * b2f(Vb[base + t * 32 + tid]);
        }
        gkr[tid] = ka;
        GV[(size_t)bh * 32 + tid] = va;
    }
    __syncthreads();
    if (tid < 32) {
        float mu = 0.f;
        for (int d = 0; d < 32; ++d) mu += gkr[d];
        mu *= (1.f / 32);
        float var = 0.f;
        for (int d = 0; d < 32; ++d) { float df = gkr[d] - mu; var += df * df; }
        var *= (1.f / 32);
        float rs = rsqrtf(var + 1e-5f);
        GK[(size_t)bh * 32 + tid] = (gkr[tid] - mu) * rs * lng_g[tid] + lng_b[tid];
    }
    __syncthreads();                 // raw K fully consumed; safe to overwrite
    if (tid < 192) {
        float mu = ksum * (1.f / 32);
        float var = ksq * (1.f / 32) - mu * mu;
        float rs = rsqrtf(var + 1e-5f);
        #pragma unroll
        for (int p2 = 0; p2 < 4; ++p2) {
            unsigned pk[4];
            #pragma unroll
            for (int e = 0; e < 4; ++e) {
                int c = p2 * 8 + e * 2;
                float v0 = (kr[c]     - mu) * rs * lnl_g[c]     + lnl_b[c];
                float v1 = (kr[c + 1] - mu) * rs * lnl_g[c + 1] + lnl_b[c + 1];
                pk[e] = (unsigned)bf16r(v0) | ((unsigned)bf16r(v1) << 16);
            }
            *(uint4*)&Kb[base + tid * 32 + p2 * 8] = make_uint4(pk[0], pk[1], pk[2], pk[3]);
        }
    }
}

// ---------------- MFMA windowed attention + landmark ------------------------
// block per (b,h); 4 waves; swapped QK^T so softmax is lane-local.
__global__ __launch_bounds__(256) void attn_mfma_kernel(
    const u16* __restrict__ Q, const u16* __restrict__ K, const u16* __restrict__ V,
    const float* __restrict__ GK, const float* __restrict__ GV, u16* __restrict__ AO)
{
    __shared__ __align__(16) u16 Ks[192][40];
    __shared__ __align__(16) u16 VTs[32][200];
    __shared__ __align__(16) u16 Ps[4][16][200];
    __shared__ float gks[32], gvs[32], sgs[192];
    const int bh = blockIdx.x, tid = threadIdx.x;
    const int lane = tid & 63, wave = tid >> 6, lrow = lane & 15, g = lane >> 4;
    const size_t base = (size_t)bh * 6144;

    if (tid < 32) { gks[tid] = GK[(size_t)bh * 32 + tid]; gvs[tid] = GV[(size_t)bh * 32 + tid]; }
    __syncthreads();
    #pragma unroll
    for (int i = 0; i < 3; ++i) {
        int f = tid + i * 256;             // 768 16B chunks
        int key = f >> 2, part = f & 3;
        *(uint4*)&Ks[key][part * 8] = *(const uint4*)&K[base + key * 32 + part * 8];
        uint4 vv = *(const uint4*)&V[base + key * 32 + part * 8];
        u16 tmp[8]; *(uint4*)tmp = vv;
        #pragma unroll
        for (int e = 0; e < 8; ++e) VTs[part * 8 + e][key] = tmp[e];
    }
    if (tid < 192) {
        float s = 0.f;
        #pragma unroll
        for (int p2 = 0; p2 < 4; ++p2) {
            short8v qv = *(const short8v*)&Q[base + tid * 32 + p2 * 8];
            #pragma unroll
            for (int j = 0; j < 8; ++j) s += b2f((u16)qv[j]) * gks[p2 * 8 + j];
        }
        sgs[tid] = s;
    }
    __syncthreads();

    for (int qi = 0; qi < 3; ++qi) {
        int qt = wave * 3 + qi;
        int q = qt * 16 + lrow;
        int ww = qt >> 2;
        int tlo = (ww == 0) ? 0 : (ww - 1) * 4;
        int thi = (ww == 2) ? 12 : (ww + 2) * 4;
        short8v qf = *(const short8v*)&Q[base + q * 32 + g * 8];
        f32x4 s[12];
        #pragma unroll
        for (int t = 0; t < 12; ++t) {
            if (t >= tlo && t < thi) {
                short8v kf = *(const short8v*)&Ks[t * 16 + lrow][g * 8];
                f32x4 z = (f32x4){0.f, 0.f, 0.f, 0.f};
                s[t] = __builtin_amdgcn_mfma_f32_16x16x32_bf16(kf, qf, z, 0, 0, 0);
            }
        }
        float sg = sgs[q];
        float m = sg;
        #pragma unroll
        for (int t = 0; t < 12; ++t) if (t >= tlo && t < thi)
            m = fmaxf(m, fmaxf(fmaxf(s[t][0], s[t][1]), fmaxf(s[t][2], s[t][3])));
        m = fmaxf(m, __shfl_xor(m, 16));
        m = fmaxf(m, __shfl_xor(m, 32));
        float l = 0.f;
        #pragma unroll
        for (int t = 0; t < 12; ++t) if (t >= tlo && t < thi) {
            #pragma unroll
            for (int r = 0; r < 4; ++r) { float p = __expf(s[t][r] - m); s[t][r] = p; l += p; }
        }
        l += __shfl_xor(l, 16);
        l += __shfl_xor(l, 32);
        float eg = __expf(sg - m);
        float inv = 1.f / (l + eg);
        float pgv = eg * inv;
        #pragma unroll
        for (int t = 0; t < 12; ++t) if (t >= tlo && t < thi) {
            unsigned u0 = (unsigned)bf16r(s[t][0] * inv) | ((unsigned)bf16r(s[t][1] * inv) << 16);
            unsigned u1 = (unsigned)bf16r(s[t][2] * inv) | ((unsigned)bf16r(s[t][3] * inv) << 16);
            *(uint2*)&Ps[wave][lrow][t * 16 + g * 4] = make_uint2(u0, u1);
        }
        f32x4 o[2] = {(f32x4){0.f,0.f,0.f,0.f}, (f32x4){0.f,0.f,0.f,0.f}};
        int slo = tlo >> 1, shi = thi >> 1;
        #pragma unroll
        for (int ss = 0; ss < 6; ++ss) if (ss >= slo && ss < shi) {
            short8v pa = *(const short8v*)&Ps[wave][lrow][ss * 32 + g * 8];
            #pragma unroll
            for (int dt = 0; dt < 2; ++dt) {
                short8v vb = *(const short8v*)&VTs[dt * 16 + lrow][ss * 32 + g * 8];
                o[dt] = __builtin_amdgcn_mfma_f32_16x16x32_bf16(pa, vb, o[dt], 0, 0, 0);
            }
        }
        int b = bh >> 3, h = bh & 7;
        #pragma unroll
        for (int r = 0; r < 4; ++r) {
            int qg = qt * 16 + 4 * g + r;
            float pg = __shfl(pgv, 4 * g + r);
            size_t rowbase = ((size_t)b * 192 + qg) * 256 + h * 32;
            #pragma unroll
            for (int dt = 0; dt < 2; ++dt) {
                int d = dt * 16 + lrow;
                AO[rowbase + d] = bf16r(o[dt][r] + pg * gvs[d]);
            }
        }
    }
}

// -------- ChanLayerNorm -> bf16 PADDED [194][194][128] (conv1 input) --------
__global__ __launch_bounds__(256) void chanln_bf16_kernel(
    const float* __restrict__ X, const float* __restrict__ g,
    const float* __restrict__ b, u16* __restrict__ out)
{
    int tid = threadIdx.x;
    int p = tid >> 2, qc = tid & 3;
    int pos = blockIdx.x * 64 + p;
    float xv[32];
    float sum = 0.f, sumsq = 0.f;
    #pragma unroll
    for (int c = 0; c < 32; ++c) {
        float v = X[(size_t)(qc * 32 + c) * SP + pos];
        xv[c] = v; sum += v; sumsq += v * v;
    }
    sum += __shfl_xor(sum, 1);  sum += __shfl_xor(sum, 2);
    sumsq += __shfl_xor(sumsq, 1); sumsq += __shfl_xor(sumsq, 2);
    float mu  = sum * (1.f / 128);
    float var = sumsq * (1.f / 128) - mu * mu;
    float inv = 1.f / (sqrtf(fmaxf(var, 0.f)) + 1e-5f);
    unsigned pk[16];
    #pragma unroll
    for (int c = 0; c < 16; ++c) {
        int c0 = qc * 32 + 2 * c;
        float v0 = (xv[2 * c]     - mu) * inv * g[c0]     + b[c0];
        float v1 = (xv[2 * c + 1] - mu) * inv * g[c0 + 1] + b[c0 + 1];
        pk[c] = (unsigned)bf16r(v0) | ((unsigned)bf16r(v1) << 16);
    }
    int y = pos / 192, x = pos - y * 192;
    uint4* dst = (uint4*)(out + ((size_t)(y + 1) * PW + x + 1) * 128 + qc * 32);
    #pragma unroll
    for (int q = 0; q < 4; ++q)
        dst[q] = make_uint4(pk[4*q], pk[4*q+1], pk[4*q+2], pk[4*q+3]);
}

// -------- conv weight repack (co,ci,3,3) f32 -> bf16 [tap][CO][CI], batched -
__global__ __launch_bounds__(256) void wtrans_kernel(
    const float* __restrict__ w, u16* __restrict__ wT, int CO, int CI)
{
    const float* wb = w + (size_t)blockIdx.y * CO * CI * 9;
    u16* wTb = wT + (size_t)blockIdx.y * CO * CI * 9;
    int gidx = blockIdx.x * 256 + threadIdx.x;   // co*CI + ci
    if (gidx >= CO * CI) return;
    const float* src = wb + (size_t)gidx * 9;
    #pragma unroll
    for (int k = 0; k < 9; ++k)
        wTb[(size_t)k * CO * CI + gidx] = bf16r(src[k]);
}

// ------------- conv as GEMM (M=36864, N=CO, K=9*CI), m97-style --------------
// inP: PADDED [194][194][CI] bf16, zero borders (no predicates anywhere).
// wT:  [9][CO][CI] bf16.
// block: 256 thr, 4 waves (2m x 2n), tile 128sp(2y x 64x) x 128co, BK=64 ci.
// A/B staged via global_load_lds (linear LDS dest, pre-swizzled source chunk),
// read back with chunk ^= (row&7) XOR swizzle (T2/ERRATA#21 pattern).
// MODE 0: out bf16 PADDED [194][194][CO], +bias, leaky (conv1 -> conv2 input).
// MODE 1: out f32 [CO][SP], +bias (conv2 -> residual X).
template<int CI, int CO, int MODE>
__global__ __launch_bounds__(256) void conv_gemm_kernel(
    const u16* __restrict__ inP, const u16* __restrict__ wT,
    const float* __restrict__ bias, void* __restrict__ outp)
{
    __shared__ __align__(16) u16 smem_u[2 * 128 * 64];   // As 16KB + Bs 16KB
    u16* As = smem_u;
    u16* Bs = smem_u + 128 * 64;

    const int bx = blockIdx.x;                 // 0..287: sp tile
    const int ty = bx / 3, tx = bx - ty * 3;
    const int y0 = ty * 2, x0 = tx * 64;
    const int co0 = blockIdx.y * 128;
    const int tid = threadIdx.x, lane = tid & 63, wave = tid >> 6;
    const int lrow = lane & 15, g = lane >> 4;
    const int wm = wave & 1, wn = wave >> 1;
    const int lane8 = lane >> 3, lanec = lane & 7;
    const int csrc = lanec ^ lane8;            // swizzled source chunk (3-bit XOR)

    // hoisted per-lane staging bases (element offsets)
    size_t aBase[4], bBase[4];
    #pragma unroll
    for (int i = 0; i < 4; ++i) {
        int rr = wave * 32 + i * 8 + lane8;            // rr&7 == lane8
        int yl = rr >> 6, xl = rr & 63;
        aBase[i] = ((size_t)(y0 + yl) * PW + x0 + xl) * CI + csrc * 8;
        bBase[i] = (size_t)(co0 + rr) * CI + csrc * 8;
    }

    f32x4 acc[4][4];
    #pragma unroll
    for (int i = 0; i < 4; ++i)
        #pragma unroll
        for (int j = 0; j < 4; ++j) acc[i][j] = (f32x4){0.f, 0.f, 0.f, 0.f};

    constexpr int CPK = CI / 64;               // K-steps per tap
    for (int kk = 0; kk < 9 * CPK; ++kk) {
        int tap = kk / CPK, cc = kk - tap * CPK;
        int ky = tap / 3, kx = tap - ky * 3;
        size_t dA = (size_t)(ky * PW + kx) * CI + cc * 64;
        size_t dB = (size_t)tap * CO * CI + cc * 64;
        #pragma unroll
        for (int i = 0; i < 4; ++i) {
            GLOAD_LDS16(inP + aBase[i] + dA, As + (wave * 32 + i * 8) * 64);
            GLOAD_LDS16(wT  + bBase[i] + dB, Bs + (wave * 32 + i * 8) * 64);
        }
        __syncthreads();
        #pragma unroll
        for (int ks = 0; ks < 2; ++ks) {
            short8v af[4], bf[4];
            #pragma unroll
            for (int fm = 0; fm < 4; ++fm) {
                int row = wm * 64 + fm * 16 + lrow;
                int ch = (ks * 4 + g) ^ (row & 7);
                af[fm] = *(const short8v*)&As[row * 64 + ch * 8];
            }
            #pragma unroll
            for (int fn = 0; fn < 4; ++fn) {
                int row = wn * 64 + fn * 16 + lrow;
                int ch = (ks * 4 + g) ^ (row & 7);
                bf[fn] = *(const short8v*)&Bs[row * 64 + ch * 8];
            }
            #pragma unroll
            for (int fm = 0; fm < 4; ++fm)
                #pragma unroll
                for (int fn = 0; fn < 4; ++fn)
                    acc[fm][fn] = __builtin_amdgcn_mfma_f32_16x16x32_bf16(
                        af[fm], bf[fn], acc[fm][fn], 0, 0, 0);
        }
        __syncthreads();
    }

    if (MODE == 0) {
        u16* out = (u16*)outp;
        #pragma unroll
        for (int fn = 0; fn < 4; ++fn) {
            int co = co0 + wn * 64 + fn * 16 + lrow;
            float bb = bias[co];
            #pragma unroll
            for (int fm = 0; fm < 4; ++fm) {
                #pragma unroll
                for (int r = 0; r < 4; ++r) {
                    int m = wm * 64 + fm * 16 + g * 4 + r;
                    int y = y0 + (m >> 6), x = x0 + (m & 63);
                    float v = acc[fm][fn][r] + bb;
                    v = (v >= 0.f) ? v : 0.01f * v;
                    out[((size_t)(y + 1) * PW + x + 1) * CO + co] = bf16r(v);
                }
            }
        }
    } else {
        float* out = (float*)outp;
        __syncthreads();
        float (*et)[17] = (float (*)[17])((char*)smem_u + wave * 4352);
        #pragma unroll
        for (int fn = 0; fn < 4; ++fn) {
            #pragma unroll
            for (int fm = 0; fm < 4; ++fm)
                #pragma unroll
                for (int r = 0; r < 4; ++r)
                    et[fm * 16 + g * 4 + r][lrow] = acc[fm][fn][r];
            __syncthreads();
            #pragma unroll
            for (int c2 = 0; c2 < 16; ++c2) {
                int co = co0 + wn * 64 + fn * 16 + c2;
                float v = et[lane][c2] + bias[co];
                out[(size_t)co * SP + (y0 + wm) * 192 + x0 + lane] = v;
            }
            __syncthreads();
        }
    }
}

// ---------------------------------------------------------------------------
extern "C" void kernel_launch(void* const* d_in, const int* in_sizes, int n_in,
                              void* d_out, int out_size, void* d_ws, size_t ws_size,
                              hipStream_t stream)
{
    const float* x_in    = (const float*)d_in[0];
    const float* ln_g    = (const float*)d_in[1];
    const float* ln_b    = (const float*)d_in[2];
    const float* Wq      = (const float*)d_in[3];
    const float* Wkv     = (const float*)d_in[4];
    const float* Wproj   = (const float*)d_in[5];
    const float* lnl_g   = (const float*)d_in[6];
    const float* lnl_b   = (const float*)d_in[7];
    const float* lng_g   = (const float*)d_in[8];
    const float* lng_b   = (const float*)d_in[9];
    const float* Wo      = (const float*)d_in[10];
    const float* bo      = (const float*)d_in[11];
    const float* cln_g   = (const float*)d_in[12];
    const float* cln_b   = (const float*)d_in[13];
    const float* conv1_w = (const float*)d_in[14];
    const float* conv1_b = (const float*)d_in[15];
    const float* conv2_w = (const float*)d_in[16];
    const float* conv2_b = (const float*)d_in[17];

    float* X = (float*)d_out;
    char* ws = (char*)d_ws;
    u16*   XN   = (u16*)(ws);                        //  9,437,184 B
    u16*   AO   = (u16*)(ws + 9437184);              // 18,874,368
    u16*   Qb   = (u16*)(ws + 28311552);             // 18,874,368
    u16*   Kb   = (u16*)(ws + 47185920);             // 18,874,368
    u16*   Vb   = (u16*)(ws + 66060288);             // 18,874,368
    float* GK   = (float*)(ws + 84934656);           //    196,608
    float* GV   = (float*)(ws + 85131264);           //    196,608
    u16*   wqT  = (u16*)(ws + 85327872);             //    262,144
    u16*   wkvT = (u16*)(ws + 85590016);             //    524,288
    u16*   woT  = (u16*)(ws + 86114304);             //    262,144
    u16*   wT1  = (u16*)(ws + 86376448);             //  2,359,296
    u16*   wT2  = (u16*)(ws + 88735744);             //  2,359,296
    // conv-phase aliases (attn buffers dead during conv):
    u16*   XNc16p = AO;          // padded [194][194][128] bf16 = 9,634,816 B
    u16*   HID16p = Qb;          // padded [194][194][512] bf16 = 38,539,264 B (Qb+Kb+part Vb)

    hipMemcpyAsync(X, x_in, (size_t)SP * NC * 4, hipMemcpyDeviceToDevice, stream);

    repack_t_kernel<<<dim3(128, 4), 256, 0, stream>>>(Wq, wqT, 128, 256);
    repack_t_kernel<<<dim3(256, 4), 256, 0, stream>>>(Wkv, wkvT, 128, 512);
    repack_t_kernel<<<dim3(128, 4), 256, 0, stream>>>(Wo, woT, 256, 128);
    wtrans_kernel<<<dim3(256, 2), 256, 0, stream>>>(conv1_w, wT1, 512, 128);
    wtrans_kernel<<<dim3(256, 2), 256, 0, stream>>>(conv2_w, wT2, 128, 512);

    const float qscale = 0.17677669529663687f;  // 32^-0.5

    for (int l = 0; l < 2; ++l) {
        for (int a = 0; a < 2; ++a) {
            int la = l * 2 + a;
            ln_rows_bf16_kernel<<<144, 256, 0, stream>>>(
                X, ln_g + la * 128, ln_b + la * 128, XN, a);
            gemm_qkv_kernel<128, 0><<<dim3(4, 288), 256, 0, stream>>>(
                XN, wqT + (size_t)la * 32768, Qb, nullptr, qscale);
            gemm_qkv_kernel<128, 1><<<dim3(8, 288), 256, 0, stream>>>(
                XN, wkvT + (size_t)la * 65536, Kb, Vb, 1.f);
            proj_lkln_kernel<<<1536, 256, 0, stream>>>(
                Kb, Vb, Wproj + la * 32, lnl_g + la * 32, lnl_b + la * 32,
                lng_g + la * 32, lng_b + la * 32, GK, GV);
            attn_mfma_kernel<<<1536, 256, 0, stream>>>(Qb, Kb, Vb, GK, GV, AO);
            if (a == 0)
                gemm_wo_kernel<0><<<dim3(2, 288), 256, 0, stream>>>(
                    AO, woT + (size_t)la * 32768, bo + la * 128, X);
            else
                gemm_wo_kernel<1><<<dim3(2, 288), 256, 0, stream>>>(
                    AO, woT + (size_t)la * 32768, bo + la * 128, X);
        }
        // zero padded conv buffers (attn phase dirtied the aliased regions;
        // interiors are fully rewritten, borders must be 0 for the conv halo)
        hipMemsetAsync(XNc16p, 0, (size_t)PSP * 128 * 2, stream);
        hipMemsetAsync(HID16p, 0, (size_t)PSP * 512 * 2, stream);
        chanln_bf16_kernel<<<576, 256, 0, stream>>>(X, cln_g + l * 128, cln_b + l * 128, XNc16p);
        conv_gemm_kernel<128, 512, 0><<<dim3(288, 4), 256, 0, stream>>>(
            XNc16p, wT1 + (size_t)l * 589824, conv1_b + l * 512, (void*)HID16p);
        conv_gemm_kernel<512, 128, 1><<<dim3(288, 1), 256, 0, stream>>>(
            HID16p, wT2 + (size_t)l * 589824, conv2_b + l * 128, (void*)X);
    }
}

// Round 9
// 1106.589 us; speedup vs baseline: 1.1957x; 1.0521x over previous
//
#include <hip/hip_runtime.h>
#include <math.h>

#define SP 36864            // 192*192 spatial
#define NC 128              // model dim
#define PW 194              // padded width (192 + 1 halo each side)
#define PSP (PW*PW)         // 37636 padded spatial

typedef unsigned short u16;
typedef __attribute__((ext_vector_type(8))) short short8v;   // 8 bf16 (4 VGPRs)
typedef __attribute__((ext_vector_type(4))) float f32x4;

static __device__ __forceinline__ u16 bf16r(float f) {
    unsigned u = __builtin_bit_cast(unsigned, f);
    u += 0x7fffu + ((u >> 16) & 1u);            // round-to-nearest-even
    return (u16)(u >> 16);
}
static __device__ __forceinline__ float b2f(u16 u) {
    unsigned v = ((unsigned)u) << 16;
    return __builtin_bit_cast(float, v);
}

#define GLOAD_LDS16(gp, lp)                                                     \
    __builtin_amdgcn_global_load_lds(                                           \
        (const __attribute__((address_space(1))) unsigned*)(gp),                \
        (__attribute__((address_space(3))) unsigned*)(lp), 16, 0, 0)

// ---------------- LayerNorm over channel -> XN bf16 [row][128] --------------
// perm==0: row=(b*192+t), X addr = c*SP + t*192 + b
// perm==1: row=(b*192+t), X addr = c*SP + b*192 + t
__global__ __launch_bounds__(256) void ln_rows_bf16_kernel(
    const float* __restrict__ X, const float* __restrict__ g,
    const float* __restrict__ b, u16* __restrict__ XN, int perm)
{
    int gid = blockIdx.x * 256 + threadIdx.x;      // 0..36863
    int i0 = gid % 192, i1 = gid / 192;
    int sp = i1 * 192 + i0;                        // coalesced along i0
    int row = (perm == 0) ? (i0 * 192 + i1) : gid;
    float sum = 0.f, sq = 0.f;
    for (int c = 0; c < NC; ++c) {
        float v = X[(size_t)c * SP + sp];
        sum += v; sq += v * v;
    }
    float mu  = sum * (1.f / NC);
    float var = sq * (1.f / NC) - mu * mu;
    float rs  = rsqrtf(var + 1e-5f);
    u16* xr = XN + (size_t)row * NC;
    for (int c0 = 0; c0 < 16; ++c0) {
        unsigned pk[4];
        #pragma unroll
        for (int e = 0; e < 4; ++e) {
            int c = c0 * 8 + e * 2;
            float v0 = (X[(size_t)c * SP + sp]       - mu) * rs * g[c]     + b[c];
            float v1 = (X[(size_t)(c + 1) * SP + sp] - mu) * rs * g[c + 1] + b[c + 1];
            pk[e] = (unsigned)bf16r(v0) | ((unsigned)bf16r(v1) << 16);
        }
        *(uint4*)&xr[c0 * 8] = make_uint4(pk[0], pk[1], pk[2], pk[3]);
    }
}

// -------- weight repack f32 [K][N] -> bf16 [N][K], batched over blockIdx.y --
__global__ __launch_bounds__(256) void repack_t_kernel(
    const float* __restrict__ in, u16* __restrict__ out, int K, int N)
{
    const float* ib = in + (size_t)blockIdx.y * K * N;
    u16* ob = out + (size_t)blockIdx.y * K * N;
    int o = blockIdx.x * 256 + threadIdx.x;
    if (o >= K * N) return;
    int n = o / K, k = o - n * K;
    ob[o] = bf16r(ib[(size_t)k * N + n]);
}

// ---------------- bf16 MFMA GEMM: A[M][KD] @ BT[N][KD]^T --------------------
// tile 128m x 64n, 4 waves (32m x 64n each), BK=64, swizzled LDS.
// MODE 0: Q epilogue (scale, -> O0[bh][t][32]); MODE 1: KV epilogue.
template<int KD, int MODE>
__global__ __launch_bounds__(256) void gemm_qkv_kernel(
    const u16* __restrict__ A, const u16* __restrict__ BT,
    u16* __restrict__ O0, u16* __restrict__ O1, float scale)
{
    __shared__ __align__(16) u16 As[128 * 64];
    __shared__ __align__(16) u16 Bs[64 * 64];
    const int m0 = blockIdx.y * 128, n0 = blockIdx.x * 64;
    const int tid = threadIdx.x, lane = tid & 63, wave = tid >> 6;
    const int lrow = lane & 15, g = lane >> 4;
    f32x4 acc[2][4];
    #pragma unroll
    for (int i = 0; i < 2; ++i)
        #pragma unroll
        for (int j = 0; j < 4; ++j) acc[i][j] = (f32x4){0.f, 0.f, 0.f, 0.f};

    for (int k0 = 0; k0 < KD; k0 += 64) {
        #pragma unroll
        for (int i = 0; i < 4; ++i) {
            int F = tid + i * 256;
            int row = F >> 3, wn = (F & 7) * 16;
            int sw = wn ^ ((row & 7) << 4);
            *(uint4*)&As[F * 8] = *(const uint4*)&A[(size_t)(m0 + row) * KD + k0 + (sw >> 1)];
        }
        #pragma unroll
        for (int i = 0; i < 2; ++i) {
            int F = tid + i * 256;
            int n = F >> 3, wn = (F & 7) * 16;
            int sw = wn ^ ((n & 7) << 4);
            *(uint4*)&Bs[F * 8] = *(const uint4*)&BT[(size_t)(n0 + n) * KD + k0 + (sw >> 1)];
        }
        __syncthreads();
        #pragma unroll
        for (int ks = 0; ks < 2; ++ks) {
            short8v af[2], bf[4];
            #pragma unroll
            for (int mt = 0; mt < 2; ++mt) {
                int row = wave * 32 + mt * 16 + lrow;
                int off = ((ks * 64 + g * 16) ^ ((row & 7) << 4)) >> 1;
                af[mt] = *(const short8v*)&As[row * 64 + off];
            }
            #pragma unroll
            for (int nt = 0; nt < 4; ++nt) {
                int n = nt * 16 + lrow;
                int off = ((ks * 64 + g * 16) ^ ((n & 7) << 4)) >> 1;
                bf[nt] = *(const short8v*)&Bs[n * 64 + off];
            }
            #pragma unroll
            for (int mt = 0; mt < 2; ++mt)
                #pragma unroll
                for (int nt = 0; nt < 4; ++nt)
                    acc[mt][nt] = __builtin_amdgcn_mfma_f32_16x16x32_bf16(
                        af[mt], bf[nt], acc[mt][nt], 0, 0, 0);
        }
        __syncthreads();
    }
    #pragma unroll
    for (int mt = 0; mt < 2; ++mt) {
        #pragma unroll
        for (int r = 0; r < 4; ++r) {
            int m = m0 + wave * 32 + mt * 16 + 4 * g + r;
            int bq = m / 192, t = m - bq * 192;
            #pragma unroll
            for (int nt = 0; nt < 4; ++nt) {
                int n = n0 + nt * 16 + lrow;
                float v = acc[mt][nt][r];
                if (MODE == 0) {
                    O0[((size_t)(bq * 8 + (n >> 5)) * 192 + t) * 32 + (n & 31)] = bf16r(v * scale);
                } else {
                    u16* dst = (n < 256) ? O0 : O1;
                    int nn = n & 255;
                    dst[((size_t)(bq * 8 + (nn >> 5)) * 192 + t) * 32 + (nn & 31)] = bf16r(v);
                }
            }
        }
    }
}

// ---------------- Wo GEMM: AO[36864][256] @ WoT[128][256]^T + bias -> X -----
// PERM0 uses row-permuted logical m so X writes are coalesced for both perms.
template<int PERM>
__global__ __launch_bounds__(256) void gemm_wo_kernel(
    const u16* __restrict__ A, const u16* __restrict__ BT,
    const float* __restrict__ bias, float* __restrict__ X)
{
    __shared__ __align__(16) char smem[64 * 132 * 4];    // 33792 B
    u16* As = (u16*)smem;                 // [128][64]
    u16* Bs = (u16*)(smem + 16384);       // [64][64]
    float (*et)[132] = (float (*)[132])smem;
    const int m0 = blockIdx.y * 128, n0 = blockIdx.x * 64;
    const int tid = threadIdx.x, lane = tid & 63, wave = tid >> 6;
    const int lrow = lane & 15, g = lane >> 4;
    f32x4 acc[2][4];
    #pragma unroll
    for (int i = 0; i < 2; ++i)
        #pragma unroll
        for (int j = 0; j < 4; ++j) acc[i][j] = (f32x4){0.f, 0.f, 0.f, 0.f};

    for (int k0 = 0; k0 < 256; k0 += 64) {
        #pragma unroll
        for (int i = 0; i < 4; ++i) {
            int F = tid + i * 256;
            int row = F >> 3, wn = (F & 7) * 16;
            int sw = wn ^ ((row & 7) << 4);
            int ml = m0 + row;
            int ra = (PERM == 0) ? ((ml % 192) * 192 + ml / 192) : ml;
            *(uint4*)&As[F * 8] = *(const uint4*)&A[(size_t)ra * 256 + k0 + (sw >> 1)];
        }
        #pragma unroll
        for (int i = 0; i < 2; ++i) {
            int F = tid + i * 256;
            int n = F >> 3, wn = (F & 7) * 16;
            int sw = wn ^ ((n & 7) << 4);
            *(uint4*)&Bs[F * 8] = *(const uint4*)&BT[(size_t)(n0 + n) * 256 + k0 + (sw >> 1)];
        }
        __syncthreads();
        #pragma unroll
        for (int ks = 0; ks < 2; ++ks) {
            short8v af[2], bf[4];
            #pragma unroll
            for (int mt = 0; mt < 2; ++mt) {
                int row = wave * 32 + mt * 16 + lrow;
                int off = ((ks * 64 + g * 16) ^ ((row & 7) << 4)) >> 1;
                af[mt] = *(const short8v*)&As[row * 64 + off];
            }
            #pragma unroll
            for (int nt = 0; nt < 4; ++nt) {
                int n = nt * 16 + lrow;
                int off = ((ks * 64 + g * 16) ^ ((n & 7) << 4)) >> 1;
                bf[nt] = *(const short8v*)&Bs[n * 64 + off];
            }
            #pragma unroll
            for (int mt = 0; mt < 2; ++mt)
                #pragma unroll
                for (int nt = 0; nt < 4; ++nt)
                    acc[mt][nt] = __builtin_amdgcn_mfma_f32_16x16x32_bf16(
                        af[mt], bf[nt], acc[mt][nt], 0, 0, 0);
        }
        __syncthreads();
    }
    __syncthreads();
    #pragma unroll
    for (int mt = 0; mt < 2; ++mt)
        #pragma unroll
        for (int nt = 0; nt < 4; ++nt)
            #pragma unroll
            for (int r = 0; r < 4; ++r)
                et[nt * 16 + lrow][wave * 32 + mt * 16 + 4 * g + r] = acc[mt][nt][r];
    __syncthreads();
    int nl = tid >> 2, mseg = (tid & 3) * 32;
    float bb = bias[n0 + nl];
    #pragma unroll
    for (int q = 0; q < 8; ++q) {
        float4 v;
        v.x = et[nl][mseg + q * 4 + 0] + bb;
        v.y = et[nl][mseg + q * 4 + 1] + bb;
        v.z = et[nl][mseg + q * 4 + 2] + bb;
        v.w = et[nl][mseg + q * 4 + 3] + bb;
        *(float4*)&X[(size_t)(n0 + nl) * SP + m0 + mseg + q * 4] = v;
    }
}

// ------ dynamic projection + landmark + fused lk-LayerNorm (bf16 K/V) -------
__global__ __launch_bounds__(256) void proj_lkln_kernel(
    u16* __restrict__ Kb, const u16* __restrict__ Vb,
    const float* __restrict__ wp, const float* __restrict__ lnl_g,
    const float* __restrict__ lnl_b, const float* __restrict__ lng_g,
    const float* __restrict__ lng_b, float* __restrict__ GK, float* __restrict__ GV)
{
    int bh = blockIdx.x, tid = threadIdx.x;
    size_t base = (size_t)bh * 6144;
    __shared__ float wps[32], sc[192], red[1], gkr[32];
    if (tid < 32) wps[tid] = wp[tid];
    __syncthreads();
    float kr[32]; float ksum = 0.f, ksq = 0.f;
    if (tid < 192) {
        float s = 0.f;
        #pragma unroll
        for (int p2 = 0; p2 < 4; ++p2) {
            short8v kv = *(const short8v*)&Kb[base + tid * 32 + p2 * 8];
            #pragma unroll
            for (int j = 0; j < 8; ++j) {
                float v = b2f((u16)kv[j]);
                kr[p2 * 8 + j] = v; s += v * wps[p2 * 8 + j];
                ksum += v; ksq += v * v;
            }
        }
        sc[tid] = s;
    }
    __syncthreads();
    if (tid < 64) {
        float m = fmaxf(fmaxf(sc[tid], sc[tid + 64]), sc[tid + 128]);
        for (int o = 32; o; o >>= 1) m = fmaxf(m, __shfl_xor(m, o));
        if (!tid) red[0] = m;
    }
    __syncthreads();
    float mx = red[0];
    if (tid < 192) sc[tid] = __expf(sc[tid] - mx);
    __syncthreads();
    if (tid < 64) {
        float s2 = sc[tid] + sc[tid + 64] + sc[tid + 128];
        for (int o = 32; o; o >>= 1) s2 += __shfl_xor(s2, o);
        if (!tid) red[0] = s2;
    }
    __syncthreads();
    float invs = 1.f / red[0];
    if (tid < 192) sc[tid] *= invs;
    __syncthreads();
    if (tid < 32) {
        float ka = 0.f, va = 0.f;
        for (int t = 0; t < 192; ++t) {
            float p = sc[t];
            ka += p * b2f(Kb[base + t * 32 + tid]);
            va += p * b2f(Vb[base + t * 32 + tid]);
        }
        gkr[tid] = ka;
        GV[(size_t)bh * 32 + tid] = va;
    }
    __syncthreads();
    if (tid < 32) {
        float mu = 0.f;
        for (int d = 0; d < 32; ++d) mu += gkr[d];
        mu *= (1.f / 32);
        float var = 0.f;
        for (int d = 0; d < 32; ++d) { float df = gkr[d] - mu; var += df * df; }
        var *= (1.f / 32);
        float rs = rsqrtf(var + 1e-5f);
        GK[(size_t)bh * 32 + tid] = (gkr[tid] - mu) * rs * lng_g[tid] + lng_b[tid];
    }
    __syncthreads();                 // raw K fully consumed; safe to overwrite
    if (tid < 192) {
        float mu = ksum * (1.f / 32);
        float var = ksq * (1.f / 32) - mu * mu;
        float rs = rsqrtf(var + 1e-5f);
        #pragma unroll
        for (int p2 = 0; p2 < 4; ++p2) {
            unsigned pk[4];
            #pragma unroll
            for (int e = 0; e < 4; ++e) {
                int c = p2 * 8 + e * 2;
                float v0 = (kr[c]     - mu) * rs * lnl_g[c]     + lnl_b[c];
                float v1 = (kr[c + 1] - mu) * rs * lnl_g[c + 1] + lnl_b[c + 1];
                pk[e] = (unsigned)bf16r(v0) | ((unsigned)bf16r(v1) << 16);
            }
            *(uint4*)&Kb[base + tid * 32 + p2 * 8] = make_uint4(pk[0], pk[1], pk[2], pk[3]);
        }
    }
}

// ---------------- MFMA windowed attention + landmark ------------------------
// block per (b,h); 4 waves; swapped QK^T so softmax is lane-local.
__global__ __launch_bounds__(256) void attn_mfma_kernel(
    const u16* __restrict__ Q, const u16* __restrict__ K, const u16* __restrict__ V,
    const float* __restrict__ GK, const float* __restrict__ GV, u16* __restrict__ AO)
{
    __shared__ __align__(16) u16 Ks[192][40];
    __shared__ __align__(16) u16 VTs[32][200];
    __shared__ __align__(16) u16 Ps[4][16][200];
    __shared__ float gks[32], gvs[32], sgs[192];
    const int bh = blockIdx.x, tid = threadIdx.x;
    const int lane = tid & 63, wave = tid >> 6, lrow = lane & 15, g = lane >> 4;
    const size_t base = (size_t)bh * 6144;

    if (tid < 32) { gks[tid] = GK[(size_t)bh * 32 + tid]; gvs[tid] = GV[(size_t)bh * 32 + tid]; }
    __syncthreads();
    #pragma unroll
    for (int i = 0; i < 3; ++i) {
        int f = tid + i * 256;             // 768 16B chunks
        int key = f >> 2, part = f & 3;
        *(uint4*)&Ks[key][part * 8] = *(const uint4*)&K[base + key * 32 + part * 8];
        uint4 vv = *(const uint4*)&V[base + key * 32 + part * 8];
        u16 tmp[8]; *(uint4*)tmp = vv;
        #pragma unroll
        for (int e = 0; e < 8; ++e) VTs[part * 8 + e][key] = tmp[e];
    }
    if (tid < 192) {
        float s = 0.f;
        #pragma unroll
        for (int p2 = 0; p2 < 4; ++p2) {
            short8v qv = *(const short8v*)&Q[base + tid * 32 + p2 * 8];
            #pragma unroll
            for (int j = 0; j < 8; ++j) s += b2f((u16)qv[j]) * gks[p2 * 8 + j];
        }
        sgs[tid] = s;
    }
    __syncthreads();

    for (int qi = 0; qi < 3; ++qi) {
        int qt = wave * 3 + qi;
        int q = qt * 16 + lrow;
        int ww = qt >> 2;
        int tlo = (ww == 0) ? 0 : (ww - 1) * 4;
        int thi = (ww == 2) ? 12 : (ww + 2) * 4;
        short8v qf = *(const short8v*)&Q[base + q * 32 + g * 8];
        f32x4 s[12];
        #pragma unroll
        for (int t = 0; t < 12; ++t) {
            if (t >= tlo && t < thi) {
                short8v kf = *(const short8v*)&Ks[t * 16 + lrow][g * 8];
                f32x4 z = (f32x4){0.f, 0.f, 0.f, 0.f};
                s[t] = __builtin_amdgcn_mfma_f32_16x16x32_bf16(kf, qf, z, 0, 0, 0);
            }
        }
        float sg = sgs[q];
        float m = sg;
        #pragma unroll
        for (int t = 0; t < 12; ++t) if (t >= tlo && t < thi)
            m = fmaxf(m, fmaxf(fmaxf(s[t][0], s[t][1]), fmaxf(s[t][2], s[t][3])));
        m = fmaxf(m, __shfl_xor(m, 16));
        m = fmaxf(m, __shfl_xor(m, 32));
        float l = 0.f;
        #pragma unroll
        for (int t = 0; t < 12; ++t) if (t >= tlo && t < thi) {
            #pragma unroll
            for (int r = 0; r < 4; ++r) { float p = __expf(s[t][r] - m); s[t][r] = p; l += p; }
        }
        l += __shfl_xor(l, 16);
        l += __shfl_xor(l, 32);
        float eg = __expf(sg - m);
        float inv = 1.f / (l + eg);
        float pgv = eg * inv;
        #pragma unroll
        for (int t = 0; t < 12; ++t) if (t >= tlo && t < thi) {
            unsigned u0 = (unsigned)bf16r(s[t][0] * inv) | ((unsigned)bf16r(s[t][1] * inv) << 16);
            unsigned u1 = (unsigned)bf16r(s[t][2] * inv) | ((unsigned)bf16r(s[t][3] * inv) << 16);
            *(uint2*)&Ps[wave][lrow][t * 16 + g * 4] = make_uint2(u0, u1);
        }
        f32x4 o[2] = {(f32x4){0.f,0.f,0.f,0.f}, (f32x4){0.f,0.f,0.f,0.f}};
        int slo = tlo >> 1, shi = thi >> 1;
        #pragma unroll
        for (int ss = 0; ss < 6; ++ss) if (ss >= slo && ss < shi) {
            short8v pa = *(const short8v*)&Ps[wave][lrow][ss * 32 + g * 8];
            #pragma unroll
            for (int dt = 0; dt < 2; ++dt) {
                short8v vb = *(const short8v*)&VTs[dt * 16 + lrow][ss * 32 + g * 8];
                o[dt] = __builtin_amdgcn_mfma_f32_16x16x32_bf16(pa, vb, o[dt], 0, 0, 0);
            }
        }
        int b = bh >> 3, h = bh & 7;
        #pragma unroll
        for (int r = 0; r < 4; ++r) {
            int qg = qt * 16 + 4 * g + r;
            float pg = __shfl(pgv, 4 * g + r);
            size_t rowbase = ((size_t)b * 192 + qg) * 256 + h * 32;
            #pragma unroll
            for (int dt = 0; dt < 2; ++dt) {
                int d = dt * 16 + lrow;
                AO[rowbase + d] = bf16r(o[dt][r] + pg * gvs[d]);
            }
        }
    }
}

// -------- ChanLayerNorm -> bf16 PADDED [194][194][128] (conv1 input) --------
__global__ __launch_bounds__(256) void chanln_bf16_kernel(
    const float* __restrict__ X, const float* __restrict__ g,
    const float* __restrict__ b, u16* __restrict__ out)
{
    int tid = threadIdx.x;
    int p = tid >> 2, qc = tid & 3;
    int pos = blockIdx.x * 64 + p;
    float xv[32];
    float sum = 0.f, sumsq = 0.f;
    #pragma unroll
    for (int c = 0; c < 32; ++c) {
        float v = X[(size_t)(qc * 32 + c) * SP + pos];
        xv[c] = v; sum += v; sumsq += v * v;
    }
    sum += __shfl_xor(sum, 1);  sum += __shfl_xor(sum, 2);
    sumsq += __shfl_xor(sumsq, 1); sumsq += __shfl_xor(sumsq, 2);
    float mu  = sum * (1.f / 128);
    float var = sumsq * (1.f / 128) - mu * mu;
    float inv = 1.f / (sqrtf(fmaxf(var, 0.f)) + 1e-5f);
    unsigned pk[16];
    #pragma unroll
    for (int c = 0; c < 16; ++c) {
        int c0 = qc * 32 + 2 * c;
        float v0 = (xv[2 * c]     - mu) * inv * g[c0]     + b[c0];
        float v1 = (xv[2 * c + 1] - mu) * inv * g[c0 + 1] + b[c0 + 1];
        pk[c] = (unsigned)bf16r(v0) | ((unsigned)bf16r(v1) << 16);
    }
    int y = pos / 192, x = pos - y * 192;
    uint4* dst = (uint4*)(out + ((size_t)(y + 1) * PW + x + 1) * 128 + qc * 32);
    #pragma unroll
    for (int q = 0; q < 4; ++q)
        dst[q] = make_uint4(pk[4*q], pk[4*q+1], pk[4*q+2], pk[4*q+3]);
}

// -------- conv weight repack (co,ci,3,3) f32 -> bf16 [tap][CO][CI], batched -
__global__ __launch_bounds__(256) void wtrans_kernel(
    const float* __restrict__ w, u16* __restrict__ wT, int CO, int CI)
{
    const float* wb = w + (size_t)blockIdx.y * CO * CI * 9;
    u16* wTb = wT + (size_t)blockIdx.y * CO * CI * 9;
    int gidx = blockIdx.x * 256 + threadIdx.x;   // co*CI + ci
    if (gidx >= CO * CI) return;
    const float* src = wb + (size_t)gidx * 9;
    #pragma unroll
    for (int k = 0; k < 9; ++k)
        wTb[(size_t)k * CO * CI + gidx] = bf16r(src[k]);
}

// ------------- conv as GEMM (M=36864, N=CO, K=9*CI), double-buffered --------
// inP: PADDED [194][194][CI] bf16, zero borders (no predicates anywhere).
// wT:  [9][CO][CI] bf16.
// block: 256 thr, 4 waves (2m x 2n), tile 128sp(2y x 64x) x 128co, BK=64 ci.
// LDS double-buffered (64 KB): stage(kk+1) issued BEFORE compute(kk); one
// __syncthreads per step (vmcnt+lgkm drain) = T3-minimum 2-phase pipeline.
// Buffer bases via offset arithmetic (no LDS pointer arrays: addrspacecast
// in a static initializer does not compile on gfx950).
// Grid: 1-D nwg = 288 * NCO, bijective XCD swizzle (m204), sp-major decode
// so each XCD owns a contiguous ty stripe (halo rows L2-resident).
// MODE 0: out bf16 PADDED [194][194][CO], +bias, leaky (conv1 -> conv2 input).
// MODE 1: out f32 [CO][SP], +bias (conv2 -> residual X).
template<int CI, int CO, int NCO, int MODE>
__global__ __launch_bounds__(256) void conv_gemm_kernel(
    const u16* __restrict__ inP, const u16* __restrict__ wT,
    const float* __restrict__ bias, void* __restrict__ outp)
{
    __shared__ __align__(16) u16 smem_u[4 * 128 * 64];   // As[2] 32KB + Bs[2] 32KB
    // layout: As(buf) = smem_u + buf*8192 ; Bs(buf) = smem_u + 16384 + buf*8192

    // bijective XCD swizzle: nwg % 8 == 0 always (288*NCO)
    const int nwg = 288 * NCO;
    const int orig = blockIdx.x;
    const int wgid = (orig & 7) * (nwg >> 3) + (orig >> 3);
    const int co_t = wgid % NCO, sp_t = wgid / NCO;      // sp-major, co fastest
    const int ty = sp_t / 3, tx = sp_t - ty * 3;
    const int y0 = ty * 2, x0 = tx * 64;
    const int co0 = co_t * 128;

    const int tid = threadIdx.x, lane = tid & 63, wave = tid >> 6;
    const int lrow = lane & 15, g = lane >> 4;
    const int wm = wave & 1, wn = wave >> 1;
    const int lane8 = lane >> 3, lanec = lane & 7;
    const int csrc = lanec ^ lane8;            // swizzled source chunk (3-bit XOR)

    // hoisted per-lane staging bases (element offsets)
    size_t aBase[4], bBase[4];
    #pragma unroll
    for (int i = 0; i < 4; ++i) {
        int rr = wave * 32 + i * 8 + lane8;            // rr&7 == lane8
        int yl = rr >> 6, xl = rr & 63;
        aBase[i] = ((size_t)(y0 + yl) * PW + x0 + xl) * CI + csrc * 8;
        bBase[i] = (size_t)(co0 + rr) * CI + csrc * 8;
    }

    constexpr int CPK = CI / 64;               // K-steps per tap
    constexpr int NK  = 9 * CPK;

    auto stage = [&](int buf, int kk) {
        int tap = kk / CPK, cc = kk - tap * CPK;
        int ky = tap / 3, kx = tap - ky * 3;
        size_t dA = (size_t)(ky * PW + kx) * CI + cc * 64;
        size_t dB = (size_t)tap * CO * CI + cc * 64;
        u16* Ad = smem_u + buf * 8192;
        u16* Bd = smem_u + 16384 + buf * 8192;
        #pragma unroll
        for (int i = 0; i < 4; ++i) {
            GLOAD_LDS16(inP + aBase[i] + dA, Ad + (wave * 32 + i * 8) * 64);
            GLOAD_LDS16(wT  + bBase[i] + dB, Bd + (wave * 32 + i * 8) * 64);
        }
    };

    f32x4 acc[4][4];
    #pragma unroll
    for (int i = 0; i < 4; ++i)
        #pragma unroll
        for (int j = 0; j < 4; ++j) acc[i][j] = (f32x4){0.f, 0.f, 0.f, 0.f};

    stage(0, 0);
    __syncthreads();
    int cur = 0;
    for (int kk = 0; kk < NK; ++kk) {
        if (kk + 1 < NK) stage(cur ^ 1, kk + 1);       // issue-early prefetch
        const u16* As = smem_u + cur * 8192;
        const u16* Bs = smem_u + 16384 + cur * 8192;
        #pragma unroll
        for (int ks = 0; ks < 2; ++ks) {
            short8v af[4], bf[4];
            #pragma unroll
            for (int fm = 0; fm < 4; ++fm) {
                int row = wm * 64 + fm * 16 + lrow;
                int ch = (ks * 4 + g) ^ (row & 7);
                af[fm] = *(const short8v*)&As[row * 64 + ch * 8];
            }
            #pragma unroll
            for (int fn = 0; fn < 4; ++fn) {
                int row = wn * 64 + fn * 16 + lrow;
                int ch = (ks * 4 + g) ^ (row & 7);
                bf[fn] = *(const short8v*)&Bs[row * 64 + ch * 8];
            }
            #pragma unroll
            for (int fm = 0; fm < 4; ++fm)
                #pragma unroll
                for (int fn = 0; fn < 4; ++fn)
                    acc[fm][fn] = __builtin_amdgcn_mfma_f32_16x16x32_bf16(
                        af[fm], bf[fn], acc[fm][fn], 0, 0, 0);
        }
        __syncthreads();            // drains vmcnt(0): next-tile stage landed
        cur ^= 1;
    }

    if (MODE == 0) {
        u16* out = (u16*)outp;
        #pragma unroll
        for (int fn = 0; fn < 4; ++fn) {
            int co = co0 + wn * 64 + fn * 16 + lrow;
            float bb = bias[co];
            #pragma unroll
            for (int fm = 0; fm < 4; ++fm) {
                #pragma unroll
                for (int r = 0; r < 4; ++r) {
                    int m = wm * 64 + fm * 16 + g * 4 + r;
                    int y = y0 + (m >> 6), x = x0 + (m & 63);
                    float v = acc[fm][fn][r] + bb;
                    v = (v >= 0.f) ? v : 0.01f * v;
                    out[((size_t)(y + 1) * PW + x + 1) * CO + co] = bf16r(v);
                }
            }
        }
    } else {
        float* out = (float*)outp;
        __syncthreads();
        float (*et)[17] = (float (*)[17])((char*)smem_u + wave * 4352);
        #pragma unroll
        for (int fn = 0; fn < 4; ++fn) {
            #pragma unroll
            for (int fm = 0; fm < 4; ++fm)
                #pragma unroll
                for (int r = 0; r < 4; ++r)
                    et[fm * 16 + g * 4 + r][lrow] = acc[fm][fn][r];
            __syncthreads();
            #pragma unroll
            for (int c2 = 0; c2 < 16; ++c2) {
                int co = co0 + wn * 64 + fn * 16 + c2;
                float v = et[lane][c2] + bias[co];
                out[(size_t)co * SP + (y0 + wm) * 192 + x0 + lane] = v;
            }
            __syncthreads();
        }
    }
}

// ---------------------------------------------------------------------------
extern "C" void kernel_launch(void* const* d_in, const int* in_sizes, int n_in,
                              void* d_out, int out_size, void* d_ws, size_t ws_size,
                              hipStream_t stream)
{
    const float* x_in    = (const float*)d_in[0];
    const float* ln_g    = (const float*)d_in[1];
    const float* ln_b    = (const float*)d_in[2];
    const float* Wq      = (const float*)d_in[3];
    const float* Wkv     = (const float*)d_in[4];
    const float* Wproj   = (const float*)d_in[5];
    const float* lnl_g   = (const float*)d_in[6];
    const float* lnl_b   = (const float*)d_in[7];
    const float* lng_g   = (const float*)d_in[8];
    const float* lng_b   = (const float*)d_in[9];
    const float* Wo      = (const float*)d_in[10];
    const float* bo      = (const float*)d_in[11];
    const float* cln_g   = (const float*)d_in[12];
    const float* cln_b   = (const float*)d_in[13];
    const float* conv1_w = (const float*)d_in[14];
    const float* conv1_b = (const float*)d_in[15];
    const float* conv2_w = (const float*)d_in[16];
    const float* conv2_b = (const float*)d_in[17];

    float* X = (float*)d_out;
    char* ws = (char*)d_ws;
    u16*   XN   = (u16*)(ws);                        //  9,437,184 B
    u16*   AO   = (u16*)(ws + 9437184);              // 18,874,368
    u16*   Qb   = (u16*)(ws + 28311552);             // 18,874,368
    u16*   Kb   = (u16*)(ws + 47185920);             // 18,874,368
    u16*   Vb   = (u16*)(ws + 66060288);             // 18,874,368
    float* GK   = (float*)(ws + 84934656);           //    196,608
    float* GV   = (float*)(ws + 85131264);           //    196,608
    u16*   wqT  = (u16*)(ws + 85327872);             //    262,144
    u16*   wkvT = (u16*)(ws + 85590016);             //    524,288
    u16*   woT  = (u16*)(ws + 86114304);             //    262,144
    u16*   wT1  = (u16*)(ws + 86376448);             //  2,359,296
    u16*   wT2  = (u16*)(ws + 88735744);             //  2,359,296
    // conv-phase aliases (attn buffers dead during conv):
    u16*   XNc16p = AO;          // padded [194][194][128] bf16 = 9,634,816 B
    u16*   HID16p = Qb;          // padded [194][194][512] bf16 = 38,539,264 B (Qb+Kb+part Vb)

    hipMemcpyAsync(X, x_in, (size_t)SP * NC * 4, hipMemcpyDeviceToDevice, stream);

    repack_t_kernel<<<dim3(128, 4), 256, 0, stream>>>(Wq, wqT, 128, 256);
    repack_t_kernel<<<dim3(256, 4), 256, 0, stream>>>(Wkv, wkvT, 128, 512);
    repack_t_kernel<<<dim3(128, 4), 256, 0, stream>>>(Wo, woT, 256, 128);
    wtrans_kernel<<<dim3(256, 2), 256, 0, stream>>>(conv1_w, wT1, 512, 128);
    wtrans_kernel<<<dim3(256, 2), 256, 0, stream>>>(conv2_w, wT2, 128, 512);

    const float qscale = 0.17677669529663687f;  // 32^-0.5

    for (int l = 0; l < 2; ++l) {
        for (int a = 0; a < 2; ++a) {
            int la = l * 2 + a;
            ln_rows_bf16_kernel<<<144, 256, 0, stream>>>(
                X, ln_g + la * 128, ln_b + la * 128, XN, a);
            gemm_qkv_kernel<128, 0><<<dim3(4, 288), 256, 0, stream>>>(
                XN, wqT + (size_t)la * 32768, Qb, nullptr, qscale);
            gemm_qkv_kernel<128, 1><<<dim3(8, 288), 256, 0, stream>>>(
                XN, wkvT + (size_t)la * 65536, Kb, Vb, 1.f);
            proj_lkln_kernel<<<1536, 256, 0, stream>>>(
                Kb, Vb, Wproj + la * 32, lnl_g + la * 32, lnl_b + la * 32,
                lng_g + la * 32, lng_b + la * 32, GK, GV);
            attn_mfma_kernel<<<1536, 256, 0, stream>>>(Qb, Kb, Vb, GK, GV, AO);
            if (a == 0)
                gemm_wo_kernel<0><<<dim3(2, 288), 256, 0, stream>>>(
                    AO, woT + (size_t)la * 32768, bo + la * 128, X);
            else
                gemm_wo_kernel<1><<<dim3(2, 288), 256, 0, stream>>>(
                    AO, woT + (size_t)la * 32768, bo + la * 128, X);
        }
        // zero padded conv buffers (attn phase dirtied the aliased regions;
        // interiors are fully rewritten, borders must be 0 for the conv halo)
        hipMemsetAsync(XNc16p, 0, (size_t)PSP * 128 * 2, stream);
        hipMemsetAsync(HID16p, 0, (size_t)PSP * 512 * 2, stream);
        chanln_bf16_kernel<<<576, 256, 0, stream>>>(X, cln_g + l * 128, cln_b + l * 128, XNc16p);
        conv_gemm_kernel<128, 512, 4, 0><<<dim3(1152), 256, 0, stream>>>(
            XNc16p, wT1 + (size_t)l * 589824, conv1_b + l * 512, (void*)HID16p);
        conv_gemm_kernel<512, 128, 1, 1><<<dim3(288), 256, 0, stream>>>(
            HID16p, wT2 + (size_t)l * 589824, conv2_b + l * 128, (void*)X);
    }
}

// Round 10
// 950.855 us; speedup vs baseline: 1.3916x; 1.1638x over previous
//
#include <hip/hip_runtime.h>
#include <math.h>

#define SP 36864            // 192*192 spatial
#define NC 128              // model dim
#define PW 194              // padded width (192 + 1 halo each side)
#define PSP (PW*PW)         // 37636 padded spatial

typedef unsigned short u16;
typedef __attribute__((ext_vector_type(8))) short short8v;   // 8 bf16 (4 VGPRs)
typedef __attribute__((ext_vector_type(4))) float f32x4;

static __device__ __forceinline__ u16 bf16r(float f) {
    unsigned u = __builtin_bit_cast(unsigned, f);
    u += 0x7fffu + ((u >> 16) & 1u);            // round-to-nearest-even
    return (u16)(u >> 16);
}
static __device__ __forceinline__ float b2f(u16 u) {
    unsigned v = ((unsigned)u) << 16;
    return __builtin_bit_cast(float, v);
}

#define GLOAD_LDS16(gp, lp)                                                     \
    __builtin_amdgcn_global_load_lds(                                           \
        (const __attribute__((address_space(1))) unsigned*)(gp),                \
        (__attribute__((address_space(3))) unsigned*)(lp), 16, 0, 0)

// ---------------- LayerNorm over channel -> XN bf16 [row][128] --------------
__global__ __launch_bounds__(256) void ln_rows_bf16_kernel(
    const float* __restrict__ X, const float* __restrict__ g,
    const float* __restrict__ b, u16* __restrict__ XN, int perm)
{
    int gid = blockIdx.x * 256 + threadIdx.x;      // 0..36863
    int i0 = gid % 192, i1 = gid / 192;
    int sp = i1 * 192 + i0;                        // coalesced along i0
    int row = (perm == 0) ? (i0 * 192 + i1) : gid;
    float sum = 0.f, sq = 0.f;
    for (int c = 0; c < NC; ++c) {
        float v = X[(size_t)c * SP + sp];
        sum += v; sq += v * v;
    }
    float mu  = sum * (1.f / NC);
    float var = sq * (1.f / NC) - mu * mu;
    float rs  = rsqrtf(var + 1e-5f);
    u16* xr = XN + (size_t)row * NC;
    for (int c0 = 0; c0 < 16; ++c0) {
        unsigned pk[4];
        #pragma unroll
        for (int e = 0; e < 4; ++e) {
            int c = c0 * 8 + e * 2;
            float v0 = (X[(size_t)c * SP + sp]       - mu) * rs * g[c]     + b[c];
            float v1 = (X[(size_t)(c + 1) * SP + sp] - mu) * rs * g[c + 1] + b[c + 1];
            pk[e] = (unsigned)bf16r(v0) | ((unsigned)bf16r(v1) << 16);
        }
        *(uint4*)&xr[c0 * 8] = make_uint4(pk[0], pk[1], pk[2], pk[3]);
    }
}

// -------- weight repack f32 [K][N] -> bf16 [N][K], batched over blockIdx.y --
__global__ __launch_bounds__(256) void repack_t_kernel(
    const float* __restrict__ in, u16* __restrict__ out, int K, int N)
{
    const float* ib = in + (size_t)blockIdx.y * K * N;
    u16* ob = out + (size_t)blockIdx.y * K * N;
    int o = blockIdx.x * 256 + threadIdx.x;
    if (o >= K * N) return;
    int n = o / K, k = o - n * K;
    ob[o] = bf16r(ib[(size_t)k * N + n]);
}

// ---------------- bf16 MFMA GEMM: A[M][KD] @ BT[N][KD]^T --------------------
template<int KD, int MODE>
__global__ __launch_bounds__(256) void gemm_qkv_kernel(
    const u16* __restrict__ A, const u16* __restrict__ BT,
    u16* __restrict__ O0, u16* __restrict__ O1, float scale)
{
    __shared__ __align__(16) u16 As[128 * 64];
    __shared__ __align__(16) u16 Bs[64 * 64];
    const int m0 = blockIdx.y * 128, n0 = blockIdx.x * 64;
    const int tid = threadIdx.x, lane = tid & 63, wave = tid >> 6;
    const int lrow = lane & 15, g = lane >> 4;
    f32x4 acc[2][4];
    #pragma unroll
    for (int i = 0; i < 2; ++i)
        #pragma unroll
        for (int j = 0; j < 4; ++j) acc[i][j] = (f32x4){0.f, 0.f, 0.f, 0.f};

    for (int k0 = 0; k0 < KD; k0 += 64) {
        #pragma unroll
        for (int i = 0; i < 4; ++i) {
            int F = tid + i * 256;
            int row = F >> 3, wn = (F & 7) * 16;
            int sw = wn ^ ((row & 7) << 4);
            *(uint4*)&As[F * 8] = *(const uint4*)&A[(size_t)(m0 + row) * KD + k0 + (sw >> 1)];
        }
        #pragma unroll
        for (int i = 0; i < 2; ++i) {
            int F = tid + i * 256;
            int n = F >> 3, wn = (F & 7) * 16;
            int sw = wn ^ ((n & 7) << 4);
            *(uint4*)&Bs[F * 8] = *(const uint4*)&BT[(size_t)(n0 + n) * KD + k0 + (sw >> 1)];
        }
        __syncthreads();
        #pragma unroll
        for (int ks = 0; ks < 2; ++ks) {
            short8v af[2], bf[4];
            #pragma unroll
            for (int mt = 0; mt < 2; ++mt) {
                int row = wave * 32 + mt * 16 + lrow;
                int off = ((ks * 64 + g * 16) ^ ((row & 7) << 4)) >> 1;
                af[mt] = *(const short8v*)&As[row * 64 + off];
            }
            #pragma unroll
            for (int nt = 0; nt < 4; ++nt) {
                int n = nt * 16 + lrow;
                int off = ((ks * 64 + g * 16) ^ ((n & 7) << 4)) >> 1;
                bf[nt] = *(const short8v*)&Bs[n * 64 + off];
            }
            #pragma unroll
            for (int mt = 0; mt < 2; ++mt)
                #pragma unroll
                for (int nt = 0; nt < 4; ++nt)
                    acc[mt][nt] = __builtin_amdgcn_mfma_f32_16x16x32_bf16(
                        af[mt], bf[nt], acc[mt][nt], 0, 0, 0);
        }
        __syncthreads();
    }
    #pragma unroll
    for (int mt = 0; mt < 2; ++mt) {
        #pragma unroll
        for (int r = 0; r < 4; ++r) {
            int m = m0 + wave * 32 + mt * 16 + 4 * g + r;
            int bq = m / 192, t = m - bq * 192;
            #pragma unroll
            for (int nt = 0; nt < 4; ++nt) {
                int n = n0 + nt * 16 + lrow;
                float v = acc[mt][nt][r];
                if (MODE == 0) {
                    O0[((size_t)(bq * 8 + (n >> 5)) * 192 + t) * 32 + (n & 31)] = bf16r(v * scale);
                } else {
                    u16* dst = (n < 256) ? O0 : O1;
                    int nn = n & 255;
                    dst[((size_t)(bq * 8 + (nn >> 5)) * 192 + t) * 32 + (nn & 31)] = bf16r(v);
                }
            }
        }
    }
}

// ---------------- Wo GEMM: AO[36864][256] @ WoT[128][256]^T + bias -> X -----
template<int PERM>
__global__ __launch_bounds__(256) void gemm_wo_kernel(
    const u16* __restrict__ A, const u16* __restrict__ BT,
    const float* __restrict__ bias, float* __restrict__ X)
{
    __shared__ __align__(16) char smem[64 * 132 * 4];    // 33792 B
    u16* As = (u16*)smem;                 // [128][64]
    u16* Bs = (u16*)(smem + 16384);       // [64][64]
    float (*et)[132] = (float (*)[132])smem;
    const int m0 = blockIdx.y * 128, n0 = blockIdx.x * 64;
    const int tid = threadIdx.x, lane = tid & 63, wave = tid >> 6;
    const int lrow = lane & 15, g = lane >> 4;
    f32x4 acc[2][4];
    #pragma unroll
    for (int i = 0; i < 2; ++i)
        #pragma unroll
        for (int j = 0; j < 4; ++j) acc[i][j] = (f32x4){0.f, 0.f, 0.f, 0.f};

    for (int k0 = 0; k0 < 256; k0 += 64) {
        #pragma unroll
        for (int i = 0; i < 4; ++i) {
            int F = tid + i * 256;
            int row = F >> 3, wn = (F & 7) * 16;
            int sw = wn ^ ((row & 7) << 4);
            int ml = m0 + row;
            int ra = (PERM == 0) ? ((ml % 192) * 192 + ml / 192) : ml;
            *(uint4*)&As[F * 8] = *(const uint4*)&A[(size_t)ra * 256 + k0 + (sw >> 1)];
        }
        #pragma unroll
        for (int i = 0; i < 2; ++i) {
            int F = tid + i * 256;
            int n = F >> 3, wn = (F & 7) * 16;
            int sw = wn ^ ((n & 7) << 4);
            *(uint4*)&Bs[F * 8] = *(const uint4*)&BT[(size_t)(n0 + n) * 256 + k0 + (sw >> 1)];
        }
        __syncthreads();
        #pragma unroll
        for (int ks = 0; ks < 2; ++ks) {
            short8v af[2], bf[4];
            #pragma unroll
            for (int mt = 0; mt < 2; ++mt) {
                int row = wave * 32 + mt * 16 + lrow;
                int off = ((ks * 64 + g * 16) ^ ((row & 7) << 4)) >> 1;
                af[mt] = *(const short8v*)&As[row * 64 + off];
            }
            #pragma unroll
            for (int nt = 0; nt < 4; ++nt) {
                int n = nt * 16 + lrow;
                int off = ((ks * 64 + g * 16) ^ ((n & 7) << 4)) >> 1;
                bf[nt] = *(const short8v*)&Bs[n * 64 + off];
            }
            #pragma unroll
            for (int mt = 0; mt < 2; ++mt)
                #pragma unroll
                for (int nt = 0; nt < 4; ++nt)
                    acc[mt][nt] = __builtin_amdgcn_mfma_f32_16x16x32_bf16(
                        af[mt], bf[nt], acc[mt][nt], 0, 0, 0);
        }
        __syncthreads();
    }
    __syncthreads();
    #pragma unroll
    for (int mt = 0; mt < 2; ++mt)
        #pragma unroll
        for (int nt = 0; nt < 4; ++nt)
            #pragma unroll
            for (int r = 0; r < 4; ++r)
                et[nt * 16 + lrow][wave * 32 + mt * 16 + 4 * g + r] = acc[mt][nt][r];
    __syncthreads();
    int nl = tid >> 2, mseg = (tid & 3) * 32;
    float bb = bias[n0 + nl];
    #pragma unroll
    for (int q = 0; q < 8; ++q) {
        float4 v;
        v.x = et[nl][mseg + q * 4 + 0] + bb;
        v.y = et[nl][mseg + q * 4 + 1] + bb;
        v.z = et[nl][mseg + q * 4 + 2] + bb;
        v.w = et[nl][mseg + q * 4 + 3] + bb;
        *(float4*)&X[(size_t)(n0 + nl) * SP + m0 + mseg + q * 4] = v;
    }
}

// ------ dynamic projection + landmark + fused lk-LayerNorm (bf16 K/V) -------
// landmark accumulation parallelized: 8 t-groups x 32 d-lanes (was 32-lane
// serial 192-loop -> 224/256 threads idle).
__global__ __launch_bounds__(256) void proj_lkln_kernel(
    u16* __restrict__ Kb, const u16* __restrict__ Vb,
    const float* __restrict__ wp, const float* __restrict__ lnl_g,
    const float* __restrict__ lnl_b, const float* __restrict__ lng_g,
    const float* __restrict__ lng_b, float* __restrict__ GK, float* __restrict__ GV)
{
    int bh = blockIdx.x, tid = threadIdx.x;
    size_t base = (size_t)bh * 6144;
    __shared__ float wps[32], sc[192], red[1], gkr[32];
    __shared__ float pkp[8][32], pvp[8][32];
    if (tid < 32) wps[tid] = wp[tid];
    __syncthreads();
    float kr[32]; float ksum = 0.f, ksq = 0.f;
    if (tid < 192) {
        float s = 0.f;
        #pragma unroll
        for (int p2 = 0; p2 < 4; ++p2) {
            short8v kv = *(const short8v*)&Kb[base + tid * 32 + p2 * 8];
            #pragma unroll
            for (int j = 0; j < 8; ++j) {
                float v = b2f((u16)kv[j]);
                kr[p2 * 8 + j] = v; s += v * wps[p2 * 8 + j];
                ksum += v; ksq += v * v;
            }
        }
        sc[tid] = s;
    }
    __syncthreads();
    if (tid < 64) {
        float m = fmaxf(fmaxf(sc[tid], sc[tid + 64]), sc[tid + 128]);
        for (int o = 32; o; o >>= 1) m = fmaxf(m, __shfl_xor(m, o));
        if (!tid) red[0] = m;
    }
    __syncthreads();
    float mx = red[0];
    if (tid < 192) sc[tid] = __expf(sc[tid] - mx);
    __syncthreads();
    if (tid < 64) {
        float s2 = sc[tid] + sc[tid + 64] + sc[tid + 128];
        for (int o = 32; o; o >>= 1) s2 += __shfl_xor(s2, o);
        if (!tid) red[0] = s2;
    }
    __syncthreads();
    float invs = 1.f / red[0];
    if (tid < 192) sc[tid] *= invs;
    __syncthreads();
    {
        int d = tid & 31, grp = tid >> 5;          // 8 groups x 24 t's
        float ka = 0.f, va = 0.f;
        for (int t = grp * 24; t < grp * 24 + 24; ++t) {
            float p = sc[t];
            ka += p * b2f(Kb[base + t * 32 + d]);
            va += p * b2f(Vb[base + t * 32 + d]);
        }
        pkp[grp][d] = ka; pvp[grp][d] = va;
    }
    __syncthreads();
    if (tid < 32) {
        float k8 = 0.f, v8 = 0.f;
        #pragma unroll
        for (int g2 = 0; g2 < 8; ++g2) { k8 += pkp[g2][tid]; v8 += pvp[g2][tid]; }
        gkr[tid] = k8;
        GV[(size_t)bh * 32 + tid] = v8;
    }
    __syncthreads();
    if (tid < 32) {
        float mu = 0.f;
        for (int d = 0; d < 32; ++d) mu += gkr[d];
        mu *= (1.f / 32);
        float var = 0.f;
        for (int d = 0; d < 32; ++d) { float df = gkr[d] - mu; var += df * df; }
        var *= (1.f / 32);
        float rs = rsqrtf(var + 1e-5f);
        GK[(size_t)bh * 32 + tid] = (gkr[tid] - mu) * rs * lng_g[tid] + lng_b[tid];
    }
    __syncthreads();                 // raw K fully consumed; safe to overwrite
    if (tid < 192) {
        float mu = ksum * (1.f / 32);
        float var = ksq * (1.f / 32) - mu * mu;
        float rs = rsqrtf(var + 1e-5f);
        #pragma unroll
        for (int p2 = 0; p2 < 4; ++p2) {
            unsigned pk[4];
            #pragma unroll
            for (int e = 0; e < 4; ++e) {
                int c = p2 * 8 + e * 2;
                float v0 = (kr[c]     - mu) * rs * lnl_g[c]     + lnl_b[c];
                float v1 = (kr[c + 1] - mu) * rs * lnl_g[c + 1] + lnl_b[c + 1];
                pk[e] = (unsigned)bf16r(v0) | ((unsigned)bf16r(v1) << 16);
            }
            *(uint4*)&Kb[base + tid * 32 + p2 * 8] = make_uint4(pk[0], pk[1], pk[2], pk[3]);
        }
    }
}

// ---------------- MFMA windowed attention + landmark ------------------------
__global__ __launch_bounds__(256) void attn_mfma_kernel(
    const u16* __restrict__ Q, const u16* __restrict__ K, const u16* __restrict__ V,
    const float* __restrict__ GK, const float* __restrict__ GV, u16* __restrict__ AO)
{
    __shared__ __align__(16) u16 Ks[192][40];
    __shared__ __align__(16) u16 VTs[32][200];
    __shared__ __align__(16) u16 Ps[4][16][200];
    __shared__ float gks[32], gvs[32], sgs[192];
    const int bh = blockIdx.x, tid = threadIdx.x;
    const int lane = tid & 63, wave = tid >> 6, lrow = lane & 15, g = lane >> 4;
    const size_t base = (size_t)bh * 6144;

    if (tid < 32) { gks[tid] = GK[(size_t)bh * 32 + tid]; gvs[tid] = GV[(size_t)bh * 32 + tid]; }
    __syncthreads();
    #pragma unroll
    for (int i = 0; i < 3; ++i) {
        int f = tid + i * 256;             // 768 16B chunks
        int key = f >> 2, part = f & 3;
        *(uint4*)&Ks[key][part * 8] = *(const uint4*)&K[base + key * 32 + part * 8];
        uint4 vv = *(const uint4*)&V[base + key * 32 + part * 8];
        u16 tmp[8]; *(uint4*)tmp = vv;
        #pragma unroll
        for (int e = 0; e < 8; ++e) VTs[part * 8 + e][key] = tmp[e];
    }
    if (tid < 192) {
        float s = 0.f;
        #pragma unroll
        for (int p2 = 0; p2 < 4; ++p2) {
            short8v qv = *(const short8v*)&Q[base + tid * 32 + p2 * 8];
            #pragma unroll
            for (int j = 0; j < 8; ++j) s += b2f((u16)qv[j]) * gks[p2 * 8 + j];
        }
        sgs[tid] = s;
    }
    __syncthreads();

    for (int qi = 0; qi < 3; ++qi) {
        int qt = wave * 3 + qi;
        int q = qt * 16 + lrow;
        int ww = qt >> 2;
        int tlo = (ww == 0) ? 0 : (ww - 1) * 4;
        int thi = (ww == 2) ? 12 : (ww + 2) * 4;
        short8v qf = *(const short8v*)&Q[base + q * 32 + g * 8];
        f32x4 s[12];
        #pragma unroll
        for (int t = 0; t < 12; ++t) {
            if (t >= tlo && t < thi) {
                short8v kf = *(const short8v*)&Ks[t * 16 + lrow][g * 8];
                f32x4 z = (f32x4){0.f, 0.f, 0.f, 0.f};
                s[t] = __builtin_amdgcn_mfma_f32_16x16x32_bf16(kf, qf, z, 0, 0, 0);
            }
        }
        float sg = sgs[q];
        float m = sg;
        #pragma unroll
        for (int t = 0; t < 12; ++t) if (t >= tlo && t < thi)
            m = fmaxf(m, fmaxf(fmaxf(s[t][0], s[t][1]), fmaxf(s[t][2], s[t][3])));
        m = fmaxf(m, __shfl_xor(m, 16));
        m = fmaxf(m, __shfl_xor(m, 32));
        float l = 0.f;
        #pragma unroll
        for (int t = 0; t < 12; ++t) if (t >= tlo && t < thi) {
            #pragma unroll
            for (int r = 0; r < 4; ++r) { float p = __expf(s[t][r] - m); s[t][r] = p; l += p; }
        }
        l += __shfl_xor(l, 16);
        l += __shfl_xor(l, 32);
        float eg = __expf(sg - m);
        float inv = 1.f / (l + eg);
        float pgv = eg * inv;
        #pragma unroll
        for (int t = 0; t < 12; ++t) if (t >= tlo && t < thi) {
            unsigned u0 = (unsigned)bf16r(s[t][0] * inv) | ((unsigned)bf16r(s[t][1] * inv) << 16);
            unsigned u1 = (unsigned)bf16r(s[t][2] * inv) | ((unsigned)bf16r(s[t][3] * inv) << 16);
            *(uint2*)&Ps[wave][lrow][t * 16 + g * 4] = make_uint2(u0, u1);
        }
        f32x4 o[2] = {(f32x4){0.f,0.f,0.f,0.f}, (f32x4){0.f,0.f,0.f,0.f}};
        int slo = tlo >> 1, shi = thi >> 1;
        #pragma unroll
        for (int ss = 0; ss < 6; ++ss) if (ss >= slo && ss < shi) {
            short8v pa = *(const short8v*)&Ps[wave][lrow][ss * 32 + g * 8];
            #pragma unroll
            for (int dt = 0; dt < 2; ++dt) {
                short8v vb = *(const short8v*)&VTs[dt * 16 + lrow][ss * 32 + g * 8];
                o[dt] = __builtin_amdgcn_mfma_f32_16x16x32_bf16(pa, vb, o[dt], 0, 0, 0);
            }
        }
        int b = bh >> 3, h = bh & 7;
        #pragma unroll
        for (int r = 0; r < 4; ++r) {
            int qg = qt * 16 + 4 * g + r;
            float pg = __shfl(pgv, 4 * g + r);
            size_t rowbase = ((size_t)b * 192 + qg) * 256 + h * 32;
            #pragma unroll
            for (int dt = 0; dt < 2; ++dt) {
                int d = dt * 16 + lrow;
                AO[rowbase + d] = bf16r(o[dt][r] + pg * gvs[d]);
            }
        }
    }
}

// -------- ChanLayerNorm -> bf16 PADDED [194][194][128] (conv1 input) --------
__global__ __launch_bounds__(256) void chanln_bf16_kernel(
    const float* __restrict__ X, const float* __restrict__ g,
    const float* __restrict__ b, u16* __restrict__ out)
{
    int tid = threadIdx.x;
    int p = tid >> 2, qc = tid & 3;
    int pos = blockIdx.x * 64 + p;
    float xv[32];
    float sum = 0.f, sumsq = 0.f;
    #pragma unroll
    for (int c = 0; c < 32; ++c) {
        float v = X[(size_t)(qc * 32 + c) * SP + pos];
        xv[c] = v; sum += v; sumsq += v * v;
    }
    sum += __shfl_xor(sum, 1);  sum += __shfl_xor(sum, 2);
    sumsq += __shfl_xor(sumsq, 1); sumsq += __shfl_xor(sumsq, 2);
    float mu  = sum * (1.f / 128);
    float var = sumsq * (1.f / 128) - mu * mu;
    float inv = 1.f / (sqrtf(fmaxf(var, 0.f)) + 1e-5f);
    unsigned pk[16];
    #pragma unroll
    for (int c = 0; c < 16; ++c) {
        int c0 = qc * 32 + 2 * c;
        float v0 = (xv[2 * c]     - mu) * inv * g[c0]     + b[c0];
        float v1 = (xv[2 * c + 1] - mu) * inv * g[c0 + 1] + b[c0 + 1];
        pk[c] = (unsigned)bf16r(v0) | ((unsigned)bf16r(v1) << 16);
    }
    int y = pos / 192, x = pos - y * 192;
    uint4* dst = (uint4*)(out + ((size_t)(y + 1) * PW + x + 1) * 128 + qc * 32);
    #pragma unroll
    for (int q = 0; q < 4; ++q)
        dst[q] = make_uint4(pk[4*q], pk[4*q+1], pk[4*q+2], pk[4*q+3]);
}

// -------- conv weight repack (co,ci,3,3) f32 -> bf16 [tap][CO][CI], batched -
__global__ __launch_bounds__(256) void wtrans_kernel(
    const float* __restrict__ w, u16* __restrict__ wT, int CO, int CI)
{
    const float* wb = w + (size_t)blockIdx.y * CO * CI * 9;
    u16* wTb = wT + (size_t)blockIdx.y * CO * CI * 9;
    int gidx = blockIdx.x * 256 + threadIdx.x;   // co*CI + ci
    if (gidx >= CO * CI) return;
    const float* src = wb + (size_t)gidx * 9;
    #pragma unroll
    for (int k = 0; k < 9; ++k)
        wTb[(size_t)k * CO * CI + gidx] = bf16r(src[k]);
}

// ------------- conv as GEMM, counted-vmcnt 2-deep pipeline ------------------
// inP: PADDED [194][194][CI] bf16, zero borders. wT: [9][CO][CI] bf16.
// MY=2: tile 128sp(2y x 64x) x 128co, 4 waves 2m x 2n, 8 loads/wave/stage.
// MY=1: tile  64sp(1y x 64x) x 128co, 4 waves (each 64sp x 32co), 6 loads/wave.
// Pipeline: stage(kk+1) -> s_waitcnt vmcnt(LOADS) (prev stage done, new one
// still in flight, T4 counted) -> s_barrier -> MFMA -> s_barrier.
// MODE 0: out bf16 PADDED, +bias, leaky.  MODE 1: out f32 [CO][SP], +bias.
template<int CI, int CO, int NCO, int MY, int MODE>
__global__ __launch_bounds__(256) void conv_gemm_kernel(
    const u16* __restrict__ inP, const u16* __restrict__ wT,
    const float* __restrict__ bias, void* __restrict__ outp)
{
    constexpr int M     = MY * 64;
    constexpr int AELEM = M * 64;              // A buf elems (bf16)
    constexpr int NSP   = (MY == 2) ? 288 : 576;
    constexpr int FN    = (MY == 2) ? 4 : 2;
    __shared__ __align__(16) u16 smem_u[2 * AELEM + 2 * 128 * 64];
    // As(buf) = smem_u + buf*AELEM ; Bs(buf) = smem_u + 2*AELEM + buf*8192

    const int nwg = NSP * NCO;                 // divisible by 8
    const int orig = blockIdx.x;
    const int wgid = (orig & 7) * (nwg >> 3) + (orig >> 3);
    const int co_t = wgid % NCO, sp_t = wgid / NCO;      // sp-major, co fastest
    const int ty = sp_t / 3, tx = sp_t - ty * 3;
    const int y0 = ty * MY, x0 = tx * 64;
    const int co0 = co_t * 128;

    const int tid = threadIdx.x, lane = tid & 63, wave = tid >> 6;
    const int lrow = lane & 15, g = lane >> 4;
    const int lane8 = lane >> 3, lanec = lane & 7;
    const int csrc = lanec ^ lane8;            // swizzled source chunk

    // hoisted per-lane staging bases (element offsets)
    size_t aBase[MY * 2], bBase[4];
    #pragma unroll
    for (int i = 0; i < MY * 2; ++i) {
        int rr = wave * (M / 4) + i * 8 + lane8;       // rr&7 == lane8
        int yl = rr >> 6, xl = rr & 63;
        aBase[i] = ((size_t)(y0 + yl) * PW + x0 + xl) * CI + csrc * 8;
    }
    #pragma unroll
    for (int i = 0; i < 4; ++i) {
        int rr = wave * 32 + i * 8 + lane8;
        bBase[i] = (size_t)(co0 + rr) * CI + csrc * 8;
    }

    constexpr int CPK = CI / 64;               // K-steps per tap
    constexpr int NK  = 9 * CPK;

    auto stage = [&](int buf, int kk) {
        int tap = kk / CPK, cc = kk - tap * CPK;
        int ky = tap / 3, kx = tap - ky * 3;
        size_t dA = (size_t)(ky * PW + kx) * CI + cc * 64;
        size_t dB = (size_t)tap * CO * CI + cc * 64;
        u16* Ad = smem_u + buf * AELEM;
        u16* Bd = smem_u + 2 * AELEM + buf * 8192;
        #pragma unroll
        for (int i = 0; i < MY * 2; ++i)
            GLOAD_LDS16(inP + aBase[i] + dA, Ad + (wave * (M / 4) + i * 8) * 64);
        #pragma unroll
        for (int i = 0; i < 4; ++i)
            GLOAD_LDS16(wT + bBase[i] + dB, Bd + (wave * 32 + i * 8) * 64);
    };

    const int aRowBase = (MY == 2) ? (wave & 1) * 64 : 0;
    const int bRowBase = (MY == 2) ? (wave >> 1) * 64 : wave * 32;

    f32x4 acc[4][FN];
    #pragma unroll
    for (int i = 0; i < 4; ++i)
        #pragma unroll
        for (int j = 0; j < FN; ++j) acc[i][j] = (f32x4){0.f, 0.f, 0.f, 0.f};

    stage(0, 0);
    int cur = 0;
    for (int kk = 0; kk < NK; ++kk) {
        if (kk + 1 < NK) {
            stage(cur ^ 1, kk + 1);            // counted prefetch stays in flight
            if constexpr (MY == 2) asm volatile("s_waitcnt vmcnt(8)" ::: "memory");
            else                   asm volatile("s_waitcnt vmcnt(6)" ::: "memory");
        } else {
            asm volatile("s_waitcnt vmcnt(0)" ::: "memory");
        }
        __builtin_amdgcn_s_barrier();
        __builtin_amdgcn_sched_barrier(0);
        const u16* As = smem_u + cur * AELEM;
        const u16* Bs = smem_u + 2 * AELEM + cur * 8192;
        #pragma unroll
        for (int ks = 0; ks < 2; ++ks) {
            short8v af[4], bf[FN];
            #pragma unroll
            for (int fm = 0; fm < 4; ++fm) {
                int row = aRowBase + fm * 16 + lrow;
                int ch = (ks * 4 + g) ^ (row & 7);
                af[fm] = *(const short8v*)&As[row * 64 + ch * 8];
            }
            #pragma unroll
            for (int fn = 0; fn < FN; ++fn) {
                int row = bRowBase + fn * 16 + lrow;
                int ch = (ks * 4 + g) ^ (row & 7);
                bf[fn] = *(const short8v*)&Bs[row * 64 + ch * 8];
            }
            #pragma unroll
            for (int fm = 0; fm < 4; ++fm)
                #pragma unroll
                for (int fn = 0; fn < FN; ++fn)
                    acc[fm][fn] = __builtin_amdgcn_mfma_f32_16x16x32_bf16(
                        af[fm], bf[fn], acc[fm][fn], 0, 0, 0);
        }
        __builtin_amdgcn_s_barrier();          // all reads done before overwrite
        cur ^= 1;
    }
    __syncthreads();

    if constexpr (MODE == 0) {
        u16* out = (u16*)outp;
        #pragma unroll
        for (int fn = 0; fn < FN; ++fn) {
            int co = co0 + bRowBase + fn * 16 + lrow;
            float bb = bias[co];
            #pragma unroll
            for (int fm = 0; fm < 4; ++fm) {
                #pragma unroll
                for (int r = 0; r < 4; ++r) {
                    int m = aRowBase + fm * 16 + g * 4 + r;
                    int y = y0 + (m >> 6), x = x0 + (m & 63);
                    float v = acc[fm][fn][r] + bb;
                    v = (v >= 0.f) ? v : 0.01f * v;
                    out[((size_t)(y + 1) * PW + x + 1) * CO + co] = bf16r(v);
                }
            }
        }
    } else {
        // MY==1: wave covers 64sp x 32co; transpose via per-wave LDS tile.
        float* out = (float*)outp;
        float (*et)[17] = (float (*)[17])((char*)smem_u + wave * 4352);
        #pragma unroll
        for (int fn = 0; fn < FN; ++fn) {
            #pragma unroll
            for (int fm = 0; fm < 4; ++fm)
                #pragma unroll
                for (int r = 0; r < 4; ++r)
                    et[fm * 16 + g * 4 + r][lrow] = acc[fm][fn][r];
            __syncthreads();
            #pragma unroll
            for (int c2 = 0; c2 < 16; ++c2) {
                int co = co0 + bRowBase + fn * 16 + c2;
                float v = et[lane][c2] + bias[co];
                out[(size_t)co * SP + y0 * 192 + x0 + lane] = v;
            }
            __syncthreads();
        }
    }
}

// ---------------------------------------------------------------------------
extern "C" void kernel_launch(void* const* d_in, const int* in_sizes, int n_in,
                              void* d_out, int out_size, void* d_ws, size_t ws_size,
                              hipStream_t stream)
{
    const float* x_in    = (const float*)d_in[0];
    const float* ln_g    = (const float*)d_in[1];
    const float* ln_b    = (const float*)d_in[2];
    const float* Wq      = (const float*)d_in[3];
    const float* Wkv     = (const float*)d_in[4];
    const float* Wproj   = (const float*)d_in[5];
    const float* lnl_g   = (const float*)d_in[6];
    const float* lnl_b   = (const float*)d_in[7];
    const float* lng_g   = (const float*)d_in[8];
    const float* lng_b   = (const float*)d_in[9];
    const float* Wo      = (const float*)d_in[10];
    const float* bo      = (const float*)d_in[11];
    const float* cln_g   = (const float*)d_in[12];
    const float* cln_b   = (const float*)d_in[13];
    const float* conv1_w = (const float*)d_in[14];
    const float* conv1_b = (const float*)d_in[15];
    const float* conv2_w = (const float*)d_in[16];
    const float* conv2_b = (const float*)d_in[17];

    float* X = (float*)d_out;
    char* ws = (char*)d_ws;
    u16*   XN   = (u16*)(ws);                        //  9,437,184 B
    u16*   AO   = (u16*)(ws + 9437184);              // 18,874,368
    u16*   Qb   = (u16*)(ws + 28311552);             // 18,874,368
    u16*   Kb   = (u16*)(ws + 47185920);             // 18,874,368
    u16*   Vb   = (u16*)(ws + 66060288);             // 18,874,368
    float* GK   = (float*)(ws + 84934656);           //    196,608
    float* GV   = (float*)(ws + 85131264);           //    196,608
    u16*   wqT  = (u16*)(ws + 85327872);             //    262,144
    u16*   wkvT = (u16*)(ws + 85590016);             //    524,288
    u16*   woT  = (u16*)(ws + 86114304);             //    262,144
    u16*   wT1  = (u16*)(ws + 86376448);             //  2,359,296
    u16*   wT2  = (u16*)(ws + 88735744);             //  2,359,296
    // conv-phase aliases (attn buffers dead during conv):
    u16*   XNc16p = AO;          // padded [194][194][128] bf16 = 9,634,816 B
    u16*   HID16p = Qb;          // padded [194][194][512] bf16 = 38,539,264 B

    hipMemcpyAsync(X, x_in, (size_t)SP * NC * 4, hipMemcpyDeviceToDevice, stream);

    repack_t_kernel<<<dim3(128, 4), 256, 0, stream>>>(Wq, wqT, 128, 256);
    repack_t_kernel<<<dim3(256, 4), 256, 0, stream>>>(Wkv, wkvT, 128, 512);
    repack_t_kernel<<<dim3(128, 4), 256, 0, stream>>>(Wo, woT, 256, 128);
    wtrans_kernel<<<dim3(256, 2), 256, 0, stream>>>(conv1_w, wT1, 512, 128);
    wtrans_kernel<<<dim3(256, 2), 256, 0, stream>>>(conv2_w, wT2, 128, 512);

    const float qscale = 0.17677669529663687f;  // 32^-0.5

    for (int l = 0; l < 2; ++l) {
        for (int a = 0; a < 2; ++a) {
            int la = l * 2 + a;
            ln_rows_bf16_kernel<<<144, 256, 0, stream>>>(
                X, ln_g + la * 128, ln_b + la * 128, XN, a);
            gemm_qkv_kernel<128, 0><<<dim3(4, 288), 256, 0, stream>>>(
                XN, wqT + (size_t)la * 32768, Qb, nullptr, qscale);
            gemm_qkv_kernel<128, 1><<<dim3(8, 288), 256, 0, stream>>>(
                XN, wkvT + (size_t)la * 65536, Kb, Vb, 1.f);
            proj_lkln_kernel<<<1536, 256, 0, stream>>>(
                Kb, Vb, Wproj + la * 32, lnl_g + la * 32, lnl_b + la * 32,
                lng_g + la * 32, lng_b + la * 32, GK, GV);
            attn_mfma_kernel<<<1536, 256, 0, stream>>>(Qb, Kb, Vb, GK, GV, AO);
            if (a == 0)
                gemm_wo_kernel<0><<<dim3(2, 288), 256, 0, stream>>>(
                    AO, woT + (size_t)la * 32768, bo + la * 128, X);
            else
                gemm_wo_kernel<1><<<dim3(2, 288), 256, 0, stream>>>(
                    AO, woT + (size_t)la * 32768, bo + la * 128, X);
        }
        // zero padded conv buffers (borders must be 0 for the conv halo)
        hipMemsetAsync(XNc16p, 0, (size_t)PSP * 128 * 2, stream);
        hipMemsetAsync(HID16p, 0, (size_t)PSP * 512 * 2, stream);
        chanln_bf16_kernel<<<576, 256, 0, stream>>>(X, cln_g + l * 128, cln_b + l * 128, XNc16p);
        conv_gemm_kernel<128, 512, 4, 2, 0><<<dim3(1152), 256, 0, stream>>>(
            XNc16p, wT1 + (size_t)l * 589824, conv1_b + l * 512, (void*)HID16p);
        conv_gemm_kernel<512, 128, 1, 1, 1><<<dim3(576), 256, 0, stream>>>(
            HID16p, wT2 + (size_t)l * 589824, conv2_b + l * 128, (void*)X);
    }
}